// Round 9
// baseline (574.946 us; speedup 1.0000x reference)
//
#include <hip/hip_runtime.h>
#include <hip/hip_bf16.h>
#include <math.h>

#define NQ 40000
#define NV 52500
#define D 256
#define NHEAD 8
#define HD 32
#define GUARD 256   // guard rows around vproj table (clamp-free sampling)

using bf16x8 = __attribute__((ext_vector_type(8))) short;
using f32x4  = __attribute__((ext_vector_type(4))) float;
typedef int v2i32 __attribute__((ext_vector_type(2)));

__device__ __forceinline__ short f2bf(float f) {
  union { __hip_bfloat16 h; short s; } u;
  u.h = __float2bfloat16(f);
  return u.s;
}
__device__ __forceinline__ float bf2f(unsigned short s) {
  return __uint_as_float((unsigned)s << 16);
}
__device__ __forceinline__ unsigned pack2(float lo, float hi) {
  return (unsigned)(unsigned short)f2bf(lo) |
         ((unsigned)(unsigned short)f2bf(hi) << 16);
}
// async global->LDS, 16B per lane, wave-uniform LDS base
__device__ __forceinline__ void gload16(const void* g, void* l) {
  __builtin_amdgcn_global_load_lds(
      (const __attribute__((address_space(1))) unsigned int*)g,
      (__attribute__((address_space(3))) unsigned int*)l, 16, 0, 0);
}

// cross-lane sum helpers: x + x[lane^K]
template<int IMM>
__device__ __forceinline__ float swz_add(float x) {   // K = 4 or 8 (ds pipe)
  return x + __int_as_float(__builtin_amdgcn_ds_swizzle(__float_as_int(x), IMM));
}
__device__ __forceinline__ float xor16_add(float x) {
#if __has_builtin(__builtin_amdgcn_permlane16_swap)
  v2i32 r = __builtin_amdgcn_permlane16_swap(__float_as_int(x), __float_as_int(x), false, false);
  return __int_as_float(r[0]) + __int_as_float(r[1]);
#else
  return x + __shfl_xor(x, 16);
#endif
}
__device__ __forceinline__ float xor32_add(float x) {
#if __has_builtin(__builtin_amdgcn_permlane32_swap)
  v2i32 r = __builtin_amdgcn_permlane32_swap(__float_as_int(x), __float_as_int(x), false, false);
  return __int_as_float(r[0]) + __int_as_float(r[1]);
#else
  return x + __shfl_xor(x, 32);
#endif
}

// ---------------------------------------------------- weight transpose->bf16
__global__ __launch_bounds__(256) void k_wt(const float* __restrict__ Wm,
                                            short* __restrict__ WT, int K, int N) {
  int idx = blockIdx.x * 256 + threadIdx.x;
  if (idx >= N * K) return;
  int n = idx / K, k = idx - n * K;
  WT[idx] = f2bf(Wm[(size_t)k * N + n]);
}

__global__ void k_catbias(const float* __restrict__ a, const float* __restrict__ b,
                          float* __restrict__ o) {
  int i = threadIdx.x;
  if (i < 192) o[i] = a[i];
  else if (i < 288) o[i] = b[i - 192];
}

// ---------------------------------------------------------------- LN1 + qp
__global__ __launch_bounds__(256) void k_ln1(const float* __restrict__ qin,
                                             const float* __restrict__ qpos,
                                             const float* __restrict__ g,
                                             const float* __restrict__ b,
                                             float* __restrict__ id_out,
                                             short* __restrict__ qp_out) {
  int wave = threadIdx.x >> 6;
  int lane = threadIdx.x & 63;
  int row  = blockIdx.x * 4 + wave;
  float4 x = ((const float4*)(qin + (size_t)row * D))[lane];
  float s  = x.x + x.y + x.z + x.w;
  float ss = x.x*x.x + x.y*x.y + x.z*x.z + x.w*x.w;
  for (int o = 32; o > 0; o >>= 1) { s += __shfl_down(s, o); ss += __shfl_down(ss, o); }
  s  = __shfl(s, 0);
  ss = __shfl(ss, 0);
  float m   = s * (1.0f / 256.0f);
  float var = ss * (1.0f / 256.0f) - m * m;
  float rs  = rsqrtf(var + 1e-5f);
  float4 gg = ((const float4*)g)[lane];
  float4 bb = ((const float4*)b)[lane];
  float4 qn;
  qn.x = (x.x - m) * rs * gg.x + bb.x;
  qn.y = (x.y - m) * rs * gg.y + bb.y;
  qn.z = (x.z - m) * rs * gg.z + bb.z;
  qn.w = (x.w - m) * rs * gg.w + bb.w;
  ((float4*)(id_out + (size_t)row * D))[lane] = qn;
  float4 p = ((const float4*)(qpos + (size_t)row * D))[lane];
  short4 o;
  o.x = f2bf(qn.x + p.x); o.y = f2bf(qn.y + p.y);
  o.z = f2bf(qn.z + p.z); o.w = f2bf(qn.w + p.w);
  ((short4*)(qp_out + (size_t)row * D))[lane] = o;
}

// ----------------------------------------------------------- LN2 -> bf16 h
__global__ __launch_bounds__(256) void k_ln2(const float* __restrict__ xin,
                                             const float* __restrict__ g,
                                             const float* __restrict__ b,
                                             short* __restrict__ h_out) {
  int wave = threadIdx.x >> 6;
  int lane = threadIdx.x & 63;
  int row  = blockIdx.x * 4 + wave;
  float4 x = ((const float4*)(xin + (size_t)row * D))[lane];
  float s  = x.x + x.y + x.z + x.w;
  float ss = x.x*x.x + x.y*x.y + x.z*x.z + x.w*x.w;
  for (int o = 32; o > 0; o >>= 1) { s += __shfl_down(s, o); ss += __shfl_down(ss, o); }
  s  = __shfl(s, 0);
  ss = __shfl(ss, 0);
  float m   = s * (1.0f / 256.0f);
  float var = ss * (1.0f / 256.0f) - m * m;
  float rs  = rsqrtf(var + 1e-5f);
  float4 gg = ((const float4*)g)[lane];
  float4 bb = ((const float4*)b)[lane];
  short4 o;
  o.x = f2bf((x.x - m) * rs * gg.x + bb.x);
  o.y = f2bf((x.y - m) * rs * gg.y + bb.y);
  o.z = f2bf((x.z - m) * rs * gg.z + bb.z);
  o.w = f2bf((x.w - m) * rs * gg.w + bb.w);
  ((short4*)(h_out + (size_t)row * D))[lane] = o;
}

// --------------------------------------------------------------- MFMA GEMM
// 128xTN tile (TN=128 or 256), BK=32, double-buffered LDS, 2-phase pipeline,
// XOR slot swizzle (both-sides), XCD-chunked block swizzle.
// TN=256: wave owns 64x128 quadrant -> 32 MFMA per barrier (2x compute/stall).
// EPI: 0 = store f32; 1 = gelu -> bf16; 2 = + R1 + R2 -> f32; 3 = Cf += v;
//      4 = store bf16
template<int EPI, int CVTA, int K, int TN>
__global__ __launch_bounds__(256, 2) void k_gemm(const void* __restrict__ Ain,
                                                 const short* __restrict__ WT,
                                                 const float* __restrict__ bias,
                                                 float* __restrict__ Cf,
                                                 short* __restrict__ Cb,
                                                 const float* __restrict__ R1,
                                                 const float* __restrict__ R2,
                                                 int M, int N) {
  constexpr int NT  = K / 32;
  constexpr int NBF = TN / 32;   // B frags per wave (4 or 8)
  constexpr int BCH = TN / 64;   // B staging chunks per wave (2 or 4)
  __shared__ short Al[2][4096];
  __shared__ short Bl[2][TN * 32];
  const int tid = threadIdx.x;

  // XCD-chunked bijective block swizzle (T1)
  const int nbx = gridDim.x;
  const int nwg = nbx * gridDim.y;
  int flat = blockIdx.y * nbx + blockIdx.x;
  {
    int xcd = flat & 7, pos = flat >> 3;
    int qq = nwg >> 3, rr = nwg & 7;
    flat = (xcd < rr ? xcd * (qq + 1) : rr * (qq + 1) + (xcd - rr) * qq) + pos;
  }
  const int n0 = (flat % nbx) * TN, m0 = (flat / nbx) * 128;

  const int w = tid >> 6, l = tid & 63;
  const int wm = (w >> 1) * 64, wn = (w & 1) * (TN / 2);
  const int lr = l & 15;

  // A staging: chunk c covers rows [16c,16c+16); lane -> row 16c+(l>>2),
  // linear LDS slot (l&3); swizzled source slot sg.
  const int c0 = w * 2, c1 = c0 + 1;
  const int sr = l >> 2;
  const int sg = (((l & 3) ^ ((l >> 3) & 3)) << 3);
  const int ar0 = min(m0 + c0 * 16 + sr, M - 1);
  const int ar1 = min(m0 + c1 * 16 + sr, M - 1);
  const short* aP0 = (const short*)Ain + (size_t)ar0 * K + sg;
  const short* aP1 = (const short*)Ain + (size_t)ar1 * K + sg;
  const float* aF0 = (const float*)Ain + (size_t)ar0 * K + sg;
  const float* aF1 = (const float*)Ain + (size_t)ar1 * K + sg;
  short* wD0 = &Al[0][(c0 * 16 + sr) * 32 + ((l & 3) << 3)];
  short* wD1 = &Al[0][(c1 * 16 + sr) * 32 + ((l & 3) << 3)];

  // B staging: BCH chunks per wave
  const short* bP[BCH];
#pragma unroll
  for (int t2 = 0; t2 < BCH; ++t2) {
    int br = min(n0 + (w * BCH + t2) * 16 + sr, N - 1);
    bP[t2] = WT + (size_t)br * K + sg;
  }

  // fragment read offsets (swizzled slot)
  const int fsw = (((l >> 4) ^ ((l >> 1) & 3)) << 3);
  const int aRd = (wm + lr) * 32 + fsw;
  const int bRd = (wn + lr) * 32 + fsw;

  f32x4 acc[4][NBF];
#pragma unroll
  for (int i = 0; i < 4; ++i)
#pragma unroll
    for (int j = 0; j < NBF; ++j) acc[i][j] = (f32x4){0, 0, 0, 0};

  // ---- prologue: stage tile 0 into buf 0
  if (CVTA) {
    float4 f00 = *(const float4*)(aF0);
    float4 f01 = *(const float4*)(aF0 + 4);
    float4 f10 = *(const float4*)(aF1);
    float4 f11 = *(const float4*)(aF1 + 4);
    int4 p0, p1;
    p0.x = pack2(f00.x, f00.y); p0.y = pack2(f00.z, f00.w);
    p0.z = pack2(f01.x, f01.y); p0.w = pack2(f01.z, f01.w);
    p1.x = pack2(f10.x, f10.y); p1.y = pack2(f10.z, f10.w);
    p1.z = pack2(f11.x, f11.y); p1.w = pack2(f11.z, f11.w);
    *(int4*)wD0 = p0;
    *(int4*)wD1 = p1;
  } else {
    gload16(aP0, &Al[0][c0 * 512]);
    gload16(aP1, &Al[0][c1 * 512]);
  }
#pragma unroll
  for (int t2 = 0; t2 < BCH; ++t2)
    gload16(bP[t2], &Bl[0][(w * BCH + t2) * 512]);
  __syncthreads();

#pragma unroll 2
  for (int t = 0; t < NT - 1; ++t) {
    const int buf = t & 1, nbuf = buf ^ 1;
    const int kn = (t + 1) * 32;
    float4 f00, f01, f10, f11;
    if (CVTA) {
      f00 = *(const float4*)(aF0 + kn);
      f01 = *(const float4*)(aF0 + kn + 4);
      f10 = *(const float4*)(aF1 + kn);
      f11 = *(const float4*)(aF1 + kn + 4);
    } else {
      gload16(aP0 + kn, &Al[nbuf][c0 * 512]);
      gload16(aP1 + kn, &Al[nbuf][c1 * 512]);
    }
#pragma unroll
    for (int t2 = 0; t2 < BCH; ++t2)
      gload16(bP[t2] + kn, &Bl[nbuf][(w * BCH + t2) * 512]);

    bf16x8 af[4], bfr[NBF];
#pragma unroll
    for (int i = 0; i < 4; ++i) af[i] = *(const bf16x8*)&Al[buf][aRd + i * 512];
#pragma unroll
    for (int j = 0; j < NBF; ++j) bfr[j] = *(const bf16x8*)&Bl[buf][bRd + j * 512];
#pragma unroll
    for (int i = 0; i < 4; ++i)
#pragma unroll
      for (int j = 0; j < NBF; ++j)
        acc[i][j] = __builtin_amdgcn_mfma_f32_16x16x32_bf16(af[i], bfr[j], acc[i][j], 0, 0, 0);

    if (CVTA) {
      int4 p0, p1;
      p0.x = pack2(f00.x, f00.y); p0.y = pack2(f00.z, f00.w);
      p0.z = pack2(f01.x, f01.y); p0.w = pack2(f01.z, f01.w);
      p1.x = pack2(f10.x, f10.y); p1.y = pack2(f10.z, f10.w);
      p1.z = pack2(f11.x, f11.y); p1.w = pack2(f11.z, f11.w);
      *(int4*)(wD0 + nbuf * 4096) = p0;
      *(int4*)(wD1 + nbuf * 4096) = p1;
    }
    __syncthreads();
  }

  {  // final tile
    const int buf = (NT - 1) & 1;
    bf16x8 af[4], bfr[NBF];
#pragma unroll
    for (int i = 0; i < 4; ++i) af[i] = *(const bf16x8*)&Al[buf][aRd + i * 512];
#pragma unroll
    for (int j = 0; j < NBF; ++j) bfr[j] = *(const bf16x8*)&Bl[buf][bRd + j * 512];
#pragma unroll
    for (int i = 0; i < 4; ++i)
#pragma unroll
      for (int j = 0; j < NBF; ++j)
        acc[i][j] = __builtin_amdgcn_mfma_f32_16x16x32_bf16(af[i], bfr[j], acc[i][j], 0, 0, 0);
  }

  const int er = (l >> 4) << 2;
  const int ec = l & 15;
#pragma unroll
  for (int i = 0; i < 4; ++i) {
#pragma unroll
    for (int j = 0; j < NBF; ++j) {
      int col = n0 + wn + j * 16 + ec;
      if (col >= N) continue;
      float bcol = bias[col];
#pragma unroll
      for (int r = 0; r < 4; ++r) {
        int row = m0 + wm + i * 16 + er + r;
        if (row >= M) continue;
        float v = acc[i][j][r] + bcol;
        size_t off = (size_t)row * N + col;
        if (EPI == 0) {
          Cf[off] = v;
        } else if (EPI == 1) {
          float u = v * (0.7978845608f + 0.0356774081f * v * v);
          float e = __expf(2.0f * u);
          float th = 1.0f - 2.0f / (e + 1.0f);
          Cb[off] = f2bf(0.5f * v * (1.0f + th));
        } else if (EPI == 2) {
          Cf[off] = v + R1[off] + R2[off];
        } else if (EPI == 3) {
          Cf[off] += v;
        } else {
          Cb[off] = f2bf(v);
        }
      }
    }
  }
}

// -------- softmax + per-point sampling meta (reads bf16 res): idx0 + 4 wgts
__global__ __launch_bounds__(256) void k_post(const unsigned short* __restrict__ res,
                                              const float* __restrict__ refp,
                                              int* __restrict__ idxA,
                                              unsigned short* __restrict__ wA) {
  int t = blockIdx.x * 256 + threadIdx.x;
  if (t >= NQ * 8) return;
  int q = t >> 3, h = t & 7;
  const unsigned short* rr = res + (size_t)q * 288;
  const unsigned short* lg = rr + 192 + h * 12;
  float lf[12];
#pragma unroll
  for (int i = 0; i < 12; ++i) lf[i] = bf2f(lg[i]);
  float mx = lf[0];
#pragma unroll
  for (int i = 1; i < 12; ++i) mx = fmaxf(mx, lf[i]);
  float e[12]; float sum = 0.0f;
#pragma unroll
  for (int i = 0; i < 12; ++i) { e[i] = expf(lf[i] - mx); sum += e[i]; }
  float inv = 1.0f / sum;

  const float dims[3] = {200.0f, 100.0f, 50.0f};
  const int   sts[3]  = {0, 40000, 50000};
#pragma unroll
  for (int l = 0; l < 3; ++l) {
    const int W = (int)dims[l];
    const float fW = dims[l];
    float rx = refp[((size_t)q * 3 + l) * 2 + 0];
    float ry = refp[((size_t)q * 3 + l) * 2 + 1];
    float invd = 1.0f / fW;
#pragma unroll
    for (int p = 0; p < 4; ++p) {
      int j = ((h * 3 + l) * 4 + p) * 2;
      float lx = rx + bf2f(rr[j + 0]) * invd;
      float ly = ry + bf2f(rr[j + 1]) * invd;
      float fx = lx * fW - 0.5f;
      float fy = ly * fW - 0.5f;
      float x0f = floorf(fx), y0f = floorf(fy);
      float tx = fx - x0f, ty = fy - y0f;
      int x0 = (int)x0f, y0 = (int)y0f;
      bool vx0 = (unsigned)x0       < (unsigned)W;
      bool vx1 = (unsigned)(x0 + 1) < (unsigned)W;
      bool vy0 = (unsigned)y0       < (unsigned)W;
      bool vy1 = (unsigned)(y0 + 1) < (unsigned)W;
      float a = e[l * 4 + p] * inv;
      float w00 = (vx0 && vy0) ? a * (1.0f - tx) * (1.0f - ty) : 0.0f;
      float w01 = (vx1 && vy0) ? a * tx * (1.0f - ty) : 0.0f;
      float w10 = (vx0 && vy1) ? a * (1.0f - tx) * ty : 0.0f;
      float w11 = (vx1 && vy1) ? a * tx * ty : 0.0f;
      int pidx = t * 12 + l * 4 + p;
      idxA[pidx] = sts[l] + y0 * W + x0;
      short4 wpk;
      wpk.x = f2bf(w00); wpk.y = f2bf(w01);
      wpk.z = f2bf(w10); wpk.w = f2bf(w11);
      *(short4*)(wA + (size_t)pidx * 4) = wpk;
    }
  }
}

// ----------------------------------------------------------- deform sampling
// vprojG points to guard region start; table begins at +GUARD rows.
__global__ __launch_bounds__(256) void k_sample(const short* __restrict__ vprojG,
                                                const int* __restrict__ idxA,
                                                const unsigned short* __restrict__ wA,
                                                short* __restrict__ smp) {
  const int lane = threadIdx.x & 63;
  const int qh   = blockIdx.x * 4 + (threadIdx.x >> 6);
  const int h = qh & 7;
  const int pg  = lane >> 4;         // point in level
  const int tap = (lane >> 2) & 3;   // dy,dx
  const int cq  = lane & 3;          // channel oct (8 ch)
  const int dy = tap >> 1, dx = tap & 1;
  const short* vb = vprojG + (size_t)GUARD * D + h * HD + cq * 8;

  float acc[8];
#pragma unroll
  for (int j = 0; j < 8; ++j) acc[j] = 0.0f;

  const int Dim[3] = {200, 100, 50};
#pragma unroll
  for (int l = 0; l < 3; ++l) {
    const int W = Dim[l];
    const int tapoff = dy * W + dx;
    int pidx = qh * 12 + l * 4 + pg;
    int idx = idxA[pidx] + tapoff;
    float wgt = __uint_as_float((unsigned)wA[(size_t)pidx * 4 + tap] << 16);
    uint4 v = *(const uint4*)(vb + (ptrdiff_t)idx * D);
    acc[0] = fmaf(wgt, __uint_as_float(v.x << 16),        acc[0]);
    acc[1] = fmaf(wgt, __uint_as_float(v.x & 0xffff0000u), acc[1]);
    acc[2] = fmaf(wgt, __uint_as_float(v.y << 16),        acc[2]);
    acc[3] = fmaf(wgt, __uint_as_float(v.y & 0xffff0000u), acc[3]);
    acc[4] = fmaf(wgt, __uint_as_float(v.z << 16),        acc[4]);
    acc[5] = fmaf(wgt, __uint_as_float(v.z & 0xffff0000u), acc[5]);
    acc[6] = fmaf(wgt, __uint_as_float(v.w << 16),        acc[6]);
    acc[7] = fmaf(wgt, __uint_as_float(v.w & 0xffff0000u), acc[7]);
  }

  // reduce taps (lane bits 2,3: ds_swizzle) and points (bits 4,5: permlane)
#pragma unroll
  for (int j = 0; j < 8; ++j) {
    float a = swz_add<0x101F>(acc[j]);   // ^4
    a = swz_add<0x201F>(a);              // ^8
    a = xor16_add(a);                    // ^16
    acc[j] = xor32_add(a);               // ^32
  }

  if (lane < 4) {
    uint4 o;
    o.x = pack2(acc[0], acc[1]);
    o.y = pack2(acc[2], acc[3]);
    o.z = pack2(acc[4], acc[5]);
    o.w = pack2(acc[6], acc[7]);
    *(uint4*)(smp + (size_t)qh * HD + cq * 8) = o;
  }
}

// ---------------------------------------------------------------------------
extern "C" void kernel_launch(void* const* d_in, const int* in_sizes, int n_in,
                              void* d_out, int out_size, void* d_ws, size_t ws_size,
                              hipStream_t stream) {
  const float* query  = (const float*)d_in[0];
  const float* value  = (const float*)d_in[1];
  const float* qpos   = (const float*)d_in[2];
  const float* refp   = (const float*)d_in[3];
  const float* n1g = (const float*)d_in[6];
  const float* n1b = (const float*)d_in[7];
  const float* Woff = (const float*)d_in[8];
  const float* boff = (const float*)d_in[9];
  const float* Wattn = (const float*)d_in[10];
  const float* battn = (const float*)d_in[11];
  const float* Wval = (const float*)d_in[12];
  const float* bval = (const float*)d_in[13];
  const float* Wout = (const float*)d_in[14];
  const float* bout = (const float*)d_in[15];
  const float* n2g = (const float*)d_in[16];
  const float* n2b = (const float*)d_in[17];
  const float* W1 = (const float*)d_in[18];
  const float* b1 = (const float*)d_in[19];
  const float* W2 = (const float*)d_in[20];
  const float* b2 = (const float*)d_in[21];

  float* out = (float*)d_out;
  char* Wb = (char*)d_ws;

  // workspace layout (time-overlaid; ~156.6 MB total)
  short* qp_bf   = (short*)Wb;                    // [0,20.48M)   ln1 -> gemm288
  float* iden    = (float*)(Wb + 20480000);       // [20.48M,61.44M) ln1 -> outproj
  int*   idxA    = (int*)(Wb + 61440000);         // [61.44M,76.8M)  post -> sample
  unsigned short* wA = (unsigned short*)(Wb + 76800000); // [76.8M,107.52M)
  short* res_bf  = (short*)(Wb + 107520000);      // 23.04MB  gemm288 -> post
  short* vprjG   = (short*)(Wb + 107520000);      // guard+26.88MB+guard -> sample
  short* vprj_bf = (short*)(Wb + 107520000 + GUARD * D * 2); // table start
  short* h_bf    = (short*)(Wb + 107520000);      // 20.48MB  ln2 -> ffn1
  short* smp_bf  = (short*)(Wb + 134662144);      // 20.48MB  sample -> outproj
  short* mid_bf  = (short*)Wb;                    // [0,81.92M) ffn1 -> ffn2
  char*  Wbase   = Wb + 155142144;
  short* WT288   = (short*)(Wbase);
  short* WTval   = (short*)(Wbase + 147456);
  short* WTout   = (short*)(Wbase + 278528);
  short* WT1     = (short*)(Wbase + 409600);
  short* WT2     = (short*)(Wbase + 933888);
  float* bias288 = (float*)(Wbase + 1458176);

  // weight prep
  k_wt<<<(192 * 256 + 255) / 256, 256, 0, stream>>>(Woff, WT288, 256, 192);
  k_wt<<<(96 * 256 + 255) / 256, 256, 0, stream>>>(Wattn, WT288 + 192 * 256, 256, 96);
  k_wt<<<(256 * 256 + 255) / 256, 256, 0, stream>>>(Wval, WTval, 256, 256);
  k_wt<<<(256 * 256 + 255) / 256, 256, 0, stream>>>(Wout, WTout, 256, 256);
  k_wt<<<(1024 * 256 + 255) / 256, 256, 0, stream>>>(W1, WT1, 256, 1024);
  k_wt<<<(256 * 1024 + 255) / 256, 256, 0, stream>>>(W2, WT2, 1024, 256);
  k_catbias<<<1, 320, 0, stream>>>(boff, battn, bias288);

  // LN1 -> iden(f32), qp(bf16)
  k_ln1<<<NQ / 4, 256, 0, stream>>>(query, qpos, n1g, n1b, iden, qp_bf);

  // offsets+attn logits GEMM (N=288) -> bf16 res  (128-wide tiles)
  k_gemm<4,0,256,128><<<dim3(3, (NQ + 127) / 128), 256, 0, stream>>>(
      qp_bf, WT288, bias288, nullptr, res_bf, nullptr, nullptr, NQ, 288);
  // softmax + sampling meta
  k_post<<<(NQ * 8 + 255) / 256, 256, 0, stream>>>(
      (const unsigned short*)res_bf, refp, idxA, wA);

  // value proj (fused f32->bf16 A staging) -> bf16 (guard-padded table)
  k_gemm<4,1,256,256><<<dim3(1, (NV + 127) / 128), 256, 0, stream>>>(
      value, WTval, bval, nullptr, vprj_bf, nullptr, nullptr, NV, 256);

  // deformable sampling -> smp(bf16)
  k_sample<<<NQ * NHEAD / 4, 256, 0, stream>>>(vprjG, idxA, wA, smp_bf);

  // out proj + residuals -> x (d_out)
  k_gemm<2,0,256,256><<<dim3(1, (NQ + 127) / 128), 256, 0, stream>>>(
      smp_bf, WTout, bout, out, nullptr, query, iden, NQ, 256);

  // LN2 -> h(bf16)
  k_ln2<<<NQ / 4, 256, 0, stream>>>(out, n2g, n2b, h_bf);

  // FFN1: gelu(h@W1+b1) -> mid(bf16)
  k_gemm<1,0,256,256><<<dim3(4, (NQ + 127) / 128), 256, 0, stream>>>(
      h_bf, WT1, b1, nullptr, mid_bf, nullptr, nullptr, NQ, 1024);

  // FFN2: x += mid@W2+b2 (in place on d_out)
  k_gemm<3,0,1024,256><<<dim3(1, (NQ + 127) / 128), 256, 0, stream>>>(
      mid_bf, WT2, b2, out, nullptr, nullptr, nullptr, NQ, 256);
}

// Round 10
// 443.214 us; speedup vs baseline: 1.2972x; 1.2972x over previous
//
#include <hip/hip_runtime.h>
#include <hip/hip_bf16.h>
#include <math.h>

#define NQ 40000
#define NV 52500
#define D 256
#define NHEAD 8
#define HD 32
#define GUARD 256   // guard rows around vproj table (clamp-free sampling)

using bf16x8 = __attribute__((ext_vector_type(8))) short;
using f32x4  = __attribute__((ext_vector_type(4))) float;
typedef int v2i32 __attribute__((ext_vector_type(2)));

__device__ __forceinline__ short f2bf(float f) {
  union { __hip_bfloat16 h; short s; } u;
  u.h = __float2bfloat16(f);
  return u.s;
}
__device__ __forceinline__ float bf2f(unsigned short s) {
  return __uint_as_float((unsigned)s << 16);
}
__device__ __forceinline__ unsigned pack2(float lo, float hi) {
  return (unsigned)(unsigned short)f2bf(lo) |
         ((unsigned)(unsigned short)f2bf(hi) << 16);
}
// async global->LDS, 16B per lane, wave-uniform LDS base
__device__ __forceinline__ void gload16(const void* g, void* l) {
  __builtin_amdgcn_global_load_lds(
      (const __attribute__((address_space(1))) unsigned int*)g,
      (__attribute__((address_space(3))) unsigned int*)l, 16, 0, 0);
}

// cross-lane sum helpers: x + x[lane^K]
template<int IMM>
__device__ __forceinline__ float swz_add(float x) {   // K = 4 or 8 (ds pipe)
  return x + __int_as_float(__builtin_amdgcn_ds_swizzle(__float_as_int(x), IMM));
}
__device__ __forceinline__ float xor16_add(float x) {
#if __has_builtin(__builtin_amdgcn_permlane16_swap)
  v2i32 r = __builtin_amdgcn_permlane16_swap(__float_as_int(x), __float_as_int(x), false, false);
  return __int_as_float(r[0]) + __int_as_float(r[1]);
#else
  return x + __shfl_xor(x, 16);
#endif
}
__device__ __forceinline__ float xor32_add(float x) {
#if __has_builtin(__builtin_amdgcn_permlane32_swap)
  v2i32 r = __builtin_amdgcn_permlane32_swap(__float_as_int(x), __float_as_int(x), false, false);
  return __int_as_float(r[0]) + __int_as_float(r[1]);
#else
  return x + __shfl_xor(x, 32);
#endif
}

// ---------------------------------------------------- weight transpose->bf16
__global__ __launch_bounds__(256) void k_wt(const float* __restrict__ Wm,
                                            short* __restrict__ WT, int K, int N) {
  int idx = blockIdx.x * 256 + threadIdx.x;
  if (idx >= N * K) return;
  int n = idx / K, k = idx - n * K;
  WT[idx] = f2bf(Wm[(size_t)k * N + n]);
}

__global__ void k_catbias(const float* __restrict__ a, const float* __restrict__ b,
                          float* __restrict__ o) {
  int i = threadIdx.x;
  if (i < 192) o[i] = a[i];
  else if (i < 288) o[i] = b[i - 192];
}

// ---------------------------------------------------------------- LN1 + qp
__global__ __launch_bounds__(256) void k_ln1(const float* __restrict__ qin,
                                             const float* __restrict__ qpos,
                                             const float* __restrict__ g,
                                             const float* __restrict__ b,
                                             float* __restrict__ id_out,
                                             short* __restrict__ qp_out) {
  int wave = threadIdx.x >> 6;
  int lane = threadIdx.x & 63;
  int row  = blockIdx.x * 4 + wave;
  float4 x = ((const float4*)(qin + (size_t)row * D))[lane];
  float s  = x.x + x.y + x.z + x.w;
  float ss = x.x*x.x + x.y*x.y + x.z*x.z + x.w*x.w;
  for (int o = 32; o > 0; o >>= 1) { s += __shfl_down(s, o); ss += __shfl_down(ss, o); }
  s  = __shfl(s, 0);
  ss = __shfl(ss, 0);
  float m   = s * (1.0f / 256.0f);
  float var = ss * (1.0f / 256.0f) - m * m;
  float rs  = rsqrtf(var + 1e-5f);
  float4 gg = ((const float4*)g)[lane];
  float4 bb = ((const float4*)b)[lane];
  float4 qn;
  qn.x = (x.x - m) * rs * gg.x + bb.x;
  qn.y = (x.y - m) * rs * gg.y + bb.y;
  qn.z = (x.z - m) * rs * gg.z + bb.z;
  qn.w = (x.w - m) * rs * gg.w + bb.w;
  ((float4*)(id_out + (size_t)row * D))[lane] = qn;
  float4 p = ((const float4*)(qpos + (size_t)row * D))[lane];
  short4 o;
  o.x = f2bf(qn.x + p.x); o.y = f2bf(qn.y + p.y);
  o.z = f2bf(qn.z + p.z); o.w = f2bf(qn.w + p.w);
  ((short4*)(qp_out + (size_t)row * D))[lane] = o;
}

// ----------------------------------------------------------- LN2 -> bf16 h
__global__ __launch_bounds__(256) void k_ln2(const float* __restrict__ xin,
                                             const float* __restrict__ g,
                                             const float* __restrict__ b,
                                             short* __restrict__ h_out) {
  int wave = threadIdx.x >> 6;
  int lane = threadIdx.x & 63;
  int row  = blockIdx.x * 4 + wave;
  float4 x = ((const float4*)(xin + (size_t)row * D))[lane];
  float s  = x.x + x.y + x.z + x.w;
  float ss = x.x*x.x + x.y*x.y + x.z*x.z + x.w*x.w;
  for (int o = 32; o > 0; o >>= 1) { s += __shfl_down(s, o); ss += __shfl_down(ss, o); }
  s  = __shfl(s, 0);
  ss = __shfl(ss, 0);
  float m   = s * (1.0f / 256.0f);
  float var = ss * (1.0f / 256.0f) - m * m;
  float rs  = rsqrtf(var + 1e-5f);
  float4 gg = ((const float4*)g)[lane];
  float4 bb = ((const float4*)b)[lane];
  short4 o;
  o.x = f2bf((x.x - m) * rs * gg.x + bb.x);
  o.y = f2bf((x.y - m) * rs * gg.y + bb.y);
  o.z = f2bf((x.z - m) * rs * gg.z + bb.z);
  o.w = f2bf((x.w - m) * rs * gg.w + bb.w);
  ((short4*)(h_out + (size_t)row * D))[lane] = o;
}

// --------------------------------------------------------------- MFMA GEMM
// 128x128 tile, BK=32, triple-buffered LDS, depth-2 async pipeline:
//   counted s_waitcnt vmcnt(4) (stage t+1 stays in flight across the barrier),
//   raw s_barrier; stage(t+2) issued after the barrier. Loads get ~2 compute
//   iterations to land. XOR slot swizzle (both-sides), XCD-chunked swizzle.
// CVTA=1 (f32 A, fused cvt) keeps the 2-phase __syncthreads structure.
// EPI: 0 = store f32; 1 = gelu -> bf16; 2 = + R1 + R2 -> f32; 3 = Cf += v;
//      4 = store bf16
template<int EPI, int CVTA, int K>
__global__ __launch_bounds__(256) void k_gemm(const void* __restrict__ Ain,
                                              const short* __restrict__ WT,
                                              const float* __restrict__ bias,
                                              float* __restrict__ Cf,
                                              short* __restrict__ Cb,
                                              const float* __restrict__ R1,
                                              const float* __restrict__ R2,
                                              int M, int N) {
  constexpr int NT = K / 32;
  __shared__ short Al[3][4096];
  __shared__ short Bl[3][4096];
  const int tid = threadIdx.x;

  // XCD-chunked bijective block swizzle (T1)
  const int nbx = gridDim.x;
  const int nwg = nbx * gridDim.y;
  int flat = blockIdx.y * nbx + blockIdx.x;
  {
    int xcd = flat & 7, pos = flat >> 3;
    int qq = nwg >> 3, rr = nwg & 7;
    flat = (xcd < rr ? xcd * (qq + 1) : rr * (qq + 1) + (xcd - rr) * qq) + pos;
  }
  const int n0 = (flat % nbx) * 128, m0 = (flat / nbx) * 128;

  const int w = tid >> 6, l = tid & 63;
  const int wm = (w >> 1) * 64, wn = (w & 1) * 64;
  const int lr = l & 15;

  const int c0 = w * 2, c1 = c0 + 1;
  const int sr = l >> 2;
  const int sg = (((l & 3) ^ ((l >> 3) & 3)) << 3);   // swizzled src slot
  const int ar0 = min(m0 + c0 * 16 + sr, M - 1);
  const int ar1 = min(m0 + c1 * 16 + sr, M - 1);
  const int br0 = min(n0 + c0 * 16 + sr, N - 1);
  const int br1 = min(n0 + c1 * 16 + sr, N - 1);
  const short* bP0 = WT + (size_t)br0 * K + sg;
  const short* bP1 = WT + (size_t)br1 * K + sg;
  const short* aP0 = (const short*)Ain + (size_t)ar0 * K + sg;
  const short* aP1 = (const short*)Ain + (size_t)ar1 * K + sg;
  const float* aF0 = (const float*)Ain + (size_t)ar0 * K + sg;
  const float* aF1 = (const float*)Ain + (size_t)ar1 * K + sg;
  short* wD0 = &Al[0][(c0 * 16 + sr) * 32 + ((l & 3) << 3)];
  short* wD1 = &Al[0][(c1 * 16 + sr) * 32 + ((l & 3) << 3)];

  const int fsw = (((l >> 4) ^ ((l >> 1) & 3)) << 3);  // swizzled read slot
  const int aRd = (wm + lr) * 32 + fsw;
  const int bRd = (wn + lr) * 32 + fsw;

  f32x4 acc[4][4];
#pragma unroll
  for (int i = 0; i < 4; ++i)
#pragma unroll
    for (int j = 0; j < 4; ++j) acc[i][j] = (f32x4){0, 0, 0, 0};

  if (CVTA) {
    // ---------------- 2-phase reg-staged cvt path (round-8 structure) ------
    {
      float4 f00 = *(const float4*)(aF0);
      float4 f01 = *(const float4*)(aF0 + 4);
      float4 f10 = *(const float4*)(aF1);
      float4 f11 = *(const float4*)(aF1 + 4);
      int4 p0, p1;
      p0.x = pack2(f00.x, f00.y); p0.y = pack2(f00.z, f00.w);
      p0.z = pack2(f01.x, f01.y); p0.w = pack2(f01.z, f01.w);
      p1.x = pack2(f10.x, f10.y); p1.y = pack2(f10.z, f10.w);
      p1.z = pack2(f11.x, f11.y); p1.w = pack2(f11.z, f11.w);
      *(int4*)wD0 = p0;
      *(int4*)wD1 = p1;
      gload16(bP0, &Bl[0][c0 * 512]);
      gload16(bP1, &Bl[0][c1 * 512]);
      __syncthreads();
    }
#pragma unroll 2
    for (int t = 0; t < NT - 1; ++t) {
      const int buf = t & 1, nbuf = buf ^ 1;
      const int kn = (t + 1) * 32;
      float4 f00 = *(const float4*)(aF0 + kn);
      float4 f01 = *(const float4*)(aF0 + kn + 4);
      float4 f10 = *(const float4*)(aF1 + kn);
      float4 f11 = *(const float4*)(aF1 + kn + 4);
      gload16(bP0 + kn, &Bl[nbuf][c0 * 512]);
      gload16(bP1 + kn, &Bl[nbuf][c1 * 512]);

      bf16x8 af[4], bfr[4];
#pragma unroll
      for (int i = 0; i < 4; ++i) {
        af[i]  = *(const bf16x8*)&Al[buf][aRd + i * 512];
        bfr[i] = *(const bf16x8*)&Bl[buf][bRd + i * 512];
      }
#pragma unroll
      for (int i = 0; i < 4; ++i)
#pragma unroll
        for (int j = 0; j < 4; ++j)
          acc[i][j] = __builtin_amdgcn_mfma_f32_16x16x32_bf16(af[i], bfr[j], acc[i][j], 0, 0, 0);

      int4 p0, p1;
      p0.x = pack2(f00.x, f00.y); p0.y = pack2(f00.z, f00.w);
      p0.z = pack2(f01.x, f01.y); p0.w = pack2(f01.z, f01.w);
      p1.x = pack2(f10.x, f10.y); p1.y = pack2(f10.z, f10.w);
      p1.z = pack2(f11.x, f11.y); p1.w = pack2(f11.z, f11.w);
      *(int4*)(wD0 + nbuf * 4096) = p0;
      *(int4*)(wD1 + nbuf * 4096) = p1;
      __syncthreads();
    }
    {
      const int buf = (NT - 1) & 1;
      bf16x8 af[4], bfr[4];
#pragma unroll
      for (int i = 0; i < 4; ++i) {
        af[i]  = *(const bf16x8*)&Al[buf][aRd + i * 512];
        bfr[i] = *(const bf16x8*)&Bl[buf][bRd + i * 512];
      }
#pragma unroll
      for (int i = 0; i < 4; ++i)
#pragma unroll
        for (int j = 0; j < 4; ++j)
          acc[i][j] = __builtin_amdgcn_mfma_f32_16x16x32_bf16(af[i], bfr[j], acc[i][j], 0, 0, 0);
    }
  } else {
    // ---------------- depth-2 counted-vmcnt pipeline, 3 buffers ------------
    // stage(t) = 4 gload16 (A:2, B:2) per wave into buf t%3.
    gload16(aP0, &Al[0][c0 * 512]);
    gload16(aP1, &Al[0][c1 * 512]);
    gload16(bP0, &Bl[0][c0 * 512]);
    gload16(bP1, &Bl[0][c1 * 512]);
    if (NT > 1) {
      gload16(aP0 + 32, &Al[1][c0 * 512]);
      gload16(aP1 + 32, &Al[1][c1 * 512]);
      gload16(bP0 + 32, &Bl[1][c0 * 512]);
      gload16(bP1 + 32, &Bl[1][c1 * 512]);
    }
#pragma unroll
    for (int t = 0; t < NT; ++t) {
      const int buf = t % 3;
      // wait: stage(t) landed; stage(t+1)'s 4 loads may stay in flight
      if (t + 1 < NT) asm volatile("s_waitcnt vmcnt(4)" ::: "memory");
      else            asm volatile("s_waitcnt vmcnt(0)" ::: "memory");
      __builtin_amdgcn_s_barrier();
      __builtin_amdgcn_sched_barrier(0);
      if (t + 2 < NT) {                 // issue stage(t+2)
        const int kn = (t + 2) * 32, nb = (t + 2) % 3;
        gload16(aP0 + kn, &Al[nb][c0 * 512]);
        gload16(aP1 + kn, &Al[nb][c1 * 512]);
        gload16(bP0 + kn, &Bl[nb][c0 * 512]);
        gload16(bP1 + kn, &Bl[nb][c1 * 512]);
      }
      bf16x8 af[4], bfr[4];
#pragma unroll
      for (int i = 0; i < 4; ++i) {
        af[i]  = *(const bf16x8*)&Al[buf][aRd + i * 512];
        bfr[i] = *(const bf16x8*)&Bl[buf][bRd + i * 512];
      }
#pragma unroll
      for (int i = 0; i < 4; ++i)
#pragma unroll
        for (int j = 0; j < 4; ++j)
          acc[i][j] = __builtin_amdgcn_mfma_f32_16x16x32_bf16(af[i], bfr[j], acc[i][j], 0, 0, 0);
    }
  }

  const int er = (l >> 4) << 2;
  const int ec = l & 15;
#pragma unroll
  for (int i = 0; i < 4; ++i) {
#pragma unroll
    for (int j = 0; j < 4; ++j) {
      int col = n0 + wn + j * 16 + ec;
      if (col >= N) continue;
      float bcol = bias[col];
#pragma unroll
      for (int r = 0; r < 4; ++r) {
        int row = m0 + wm + i * 16 + er + r;
        if (row >= M) continue;
        float v = acc[i][j][r] + bcol;
        size_t off = (size_t)row * N + col;
        if (EPI == 0) {
          Cf[off] = v;
        } else if (EPI == 1) {
          float u = v * (0.7978845608f + 0.0356774081f * v * v);
          float e = __expf(2.0f * u);
          float th = 1.0f - 2.0f / (e + 1.0f);
          Cb[off] = f2bf(0.5f * v * (1.0f + th));
        } else if (EPI == 2) {
          Cf[off] = v + R1[off] + R2[off];
        } else if (EPI == 3) {
          Cf[off] += v;
        } else {
          Cb[off] = f2bf(v);
        }
      }
    }
  }
}

// -------- softmax + per-point sampling meta (reads bf16 res): idx0 + 4 wgts
__global__ __launch_bounds__(256) void k_post(const unsigned short* __restrict__ res,
                                              const float* __restrict__ refp,
                                              int* __restrict__ idxA,
                                              unsigned short* __restrict__ wA) {
  int t = blockIdx.x * 256 + threadIdx.x;
  if (t >= NQ * 8) return;
  int q = t >> 3, h = t & 7;
  const unsigned short* rr = res + (size_t)q * 288;
  const unsigned short* lg = rr + 192 + h * 12;
  float lf[12];
#pragma unroll
  for (int i = 0; i < 12; ++i) lf[i] = bf2f(lg[i]);
  float mx = lf[0];
#pragma unroll
  for (int i = 1; i < 12; ++i) mx = fmaxf(mx, lf[i]);
  float e[12]; float sum = 0.0f;
#pragma unroll
  for (int i = 0; i < 12; ++i) { e[i] = expf(lf[i] - mx); sum += e[i]; }
  float inv = 1.0f / sum;

  const float dims[3] = {200.0f, 100.0f, 50.0f};
  const int   sts[3]  = {0, 40000, 50000};
#pragma unroll
  for (int l = 0; l < 3; ++l) {
    const int W = (int)dims[l];
    const float fW = dims[l];
    float rx = refp[((size_t)q * 3 + l) * 2 + 0];
    float ry = refp[((size_t)q * 3 + l) * 2 + 1];
    float invd = 1.0f / fW;
#pragma unroll
    for (int p = 0; p < 4; ++p) {
      int j = ((h * 3 + l) * 4 + p) * 2;
      float lx = rx + bf2f(rr[j + 0]) * invd;
      float ly = ry + bf2f(rr[j + 1]) * invd;
      float fx = lx * fW - 0.5f;
      float fy = ly * fW - 0.5f;
      float x0f = floorf(fx), y0f = floorf(fy);
      float tx = fx - x0f, ty = fy - y0f;
      int x0 = (int)x0f, y0 = (int)y0f;
      bool vx0 = (unsigned)x0       < (unsigned)W;
      bool vx1 = (unsigned)(x0 + 1) < (unsigned)W;
      bool vy0 = (unsigned)y0       < (unsigned)W;
      bool vy1 = (unsigned)(y0 + 1) < (unsigned)W;
      float a = e[l * 4 + p] * inv;
      float w00 = (vx0 && vy0) ? a * (1.0f - tx) * (1.0f - ty) : 0.0f;
      float w01 = (vx1 && vy0) ? a * tx * (1.0f - ty) : 0.0f;
      float w10 = (vx0 && vy1) ? a * (1.0f - tx) * ty : 0.0f;
      float w11 = (vx1 && vy1) ? a * tx * ty : 0.0f;
      int pidx = t * 12 + l * 4 + p;
      idxA[pidx] = sts[l] + y0 * W + x0;
      short4 wpk;
      wpk.x = f2bf(w00); wpk.y = f2bf(w01);
      wpk.z = f2bf(w10); wpk.w = f2bf(w11);
      *(short4*)(wA + (size_t)pidx * 4) = wpk;
    }
  }
}

// ----------------------------------------------------------- deform sampling
// vprojG points to guard region start; table begins at +GUARD rows.
__global__ __launch_bounds__(256) void k_sample(const short* __restrict__ vprojG,
                                                const int* __restrict__ idxA,
                                                const unsigned short* __restrict__ wA,
                                                short* __restrict__ smp) {
  const int lane = threadIdx.x & 63;
  const int qh   = blockIdx.x * 4 + (threadIdx.x >> 6);
  const int h = qh & 7;
  const int pg  = lane >> 4;         // point in level
  const int tap = (lane >> 2) & 3;   // dy,dx
  const int cq  = lane & 3;          // channel oct (8 ch)
  const int dy = tap >> 1, dx = tap & 1;
  const short* vb = vprojG + (size_t)GUARD * D + h * HD + cq * 8;

  float acc[8];
#pragma unroll
  for (int j = 0; j < 8; ++j) acc[j] = 0.0f;

  const int Dim[3] = {200, 100, 50};
#pragma unroll
  for (int l = 0; l < 3; ++l) {
    const int W = Dim[l];
    const int tapoff = dy * W + dx;
    int pidx = qh * 12 + l * 4 + pg;
    int idx = idxA[pidx] + tapoff;
    float wgt = __uint_as_float((unsigned)wA[(size_t)pidx * 4 + tap] << 16);
    uint4 v = *(const uint4*)(vb + (ptrdiff_t)idx * D);
    acc[0] = fmaf(wgt, __uint_as_float(v.x << 16),        acc[0]);
    acc[1] = fmaf(wgt, __uint_as_float(v.x & 0xffff0000u), acc[1]);
    acc[2] = fmaf(wgt, __uint_as_float(v.y << 16),        acc[2]);
    acc[3] = fmaf(wgt, __uint_as_float(v.y & 0xffff0000u), acc[3]);
    acc[4] = fmaf(wgt, __uint_as_float(v.z << 16),        acc[4]);
    acc[5] = fmaf(wgt, __uint_as_float(v.z & 0xffff0000u), acc[5]);
    acc[6] = fmaf(wgt, __uint_as_float(v.w << 16),        acc[6]);
    acc[7] = fmaf(wgt, __uint_as_float(v.w & 0xffff0000u), acc[7]);
  }

  // reduce taps (lane bits 2,3: ds_swizzle) and points (bits 4,5: permlane)
#pragma unroll
  for (int j = 0; j < 8; ++j) {
    float a = swz_add<0x101F>(acc[j]);   // ^4
    a = swz_add<0x201F>(a);              // ^8
    a = xor16_add(a);                    // ^16
    acc[j] = xor32_add(a);               // ^32
  }

  if (lane < 4) {
    uint4 o;
    o.x = pack2(acc[0], acc[1]);
    o.y = pack2(acc[2], acc[3]);
    o.z = pack2(acc[4], acc[5]);
    o.w = pack2(acc[6], acc[7]);
    *(uint4*)(smp + (size_t)qh * HD + cq * 8) = o;
  }
}

// ---------------------------------------------------------------------------
extern "C" void kernel_launch(void* const* d_in, const int* in_sizes, int n_in,
                              void* d_out, int out_size, void* d_ws, size_t ws_size,
                              hipStream_t stream) {
  const float* query  = (const float*)d_in[0];
  const float* value  = (const float*)d_in[1];
  const float* qpos   = (const float*)d_in[2];
  const float* refp   = (const float*)d_in[3];
  const float* n1g = (const float*)d_in[6];
  const float* n1b = (const float*)d_in[7];
  const float* Woff = (const float*)d_in[8];
  const float* boff = (const float*)d_in[9];
  const float* Wattn = (const float*)d_in[10];
  const float* battn = (const float*)d_in[11];
  const float* Wval = (const float*)d_in[12];
  const float* bval = (const float*)d_in[13];
  const float* Wout = (const float*)d_in[14];
  const float* bout = (const float*)d_in[15];
  const float* n2g = (const float*)d_in[16];
  const float* n2b = (const float*)d_in[17];
  const float* W1 = (const float*)d_in[18];
  const float* b1 = (const float*)d_in[19];
  const float* W2 = (const float*)d_in[20];
  const float* b2 = (const float*)d_in[21];

  float* out = (float*)d_out;
  char* Wb = (char*)d_ws;

  // workspace layout (time-overlaid; ~156.6 MB total)
  short* qp_bf   = (short*)Wb;                    // [0,20.48M)   ln1 -> gemm288
  float* iden    = (float*)(Wb + 20480000);       // [20.48M,61.44M) ln1 -> outproj
  int*   idxA    = (int*)(Wb + 61440000);         // [61.44M,76.8M)  post -> sample
  unsigned short* wA = (unsigned short*)(Wb + 76800000); // [76.8M,107.52M)
  short* res_bf  = (short*)(Wb + 107520000);      // 23.04MB  gemm288 -> post
  short* vprjG   = (short*)(Wb + 107520000);      // guard+26.88MB+guard -> sample
  short* vprj_bf = (short*)(Wb + 107520000 + GUARD * D * 2); // table start
  short* h_bf    = (short*)(Wb + 107520000);      // 20.48MB  ln2 -> ffn1
  short* smp_bf  = (short*)(Wb + 134662144);      // 20.48MB  sample -> outproj
  short* mid_bf  = (short*)Wb;                    // [0,81.92M) ffn1 -> ffn2
  char*  Wbase   = Wb + 155142144;
  short* WT288   = (short*)(Wbase);
  short* WTval   = (short*)(Wbase + 147456);
  short* WTout   = (short*)(Wbase + 278528);
  short* WT1     = (short*)(Wbase + 409600);
  short* WT2     = (short*)(Wbase + 933888);
  float* bias288 = (float*)(Wbase + 1458176);

  // weight prep
  k_wt<<<(192 * 256 + 255) / 256, 256, 0, stream>>>(Woff, WT288, 256, 192);
  k_wt<<<(96 * 256 + 255) / 256, 256, 0, stream>>>(Wattn, WT288 + 192 * 256, 256, 96);
  k_wt<<<(256 * 256 + 255) / 256, 256, 0, stream>>>(Wval, WTval, 256, 256);
  k_wt<<<(256 * 256 + 255) / 256, 256, 0, stream>>>(Wout, WTout, 256, 256);
  k_wt<<<(1024 * 256 + 255) / 256, 256, 0, stream>>>(W1, WT1, 256, 1024);
  k_wt<<<(256 * 1024 + 255) / 256, 256, 0, stream>>>(W2, WT2, 1024, 256);
  k_catbias<<<1, 320, 0, stream>>>(boff, battn, bias288);

  // LN1 -> iden(f32), qp(bf16)
  k_ln1<<<NQ / 4, 256, 0, stream>>>(query, qpos, n1g, n1b, iden, qp_bf);

  // offsets+attn logits GEMM (N=288) -> bf16 res
  k_gemm<4,0,256><<<dim3(3, (NQ + 127) / 128), 256, 0, stream>>>(
      qp_bf, WT288, bias288, nullptr, res_bf, nullptr, nullptr, NQ, 288);
  // softmax + sampling meta
  k_post<<<(NQ * 8 + 255) / 256, 256, 0, stream>>>(
      (const unsigned short*)res_bf, refp, idxA, wA);

  // value proj (fused f32->bf16 A staging) -> bf16 (guard-padded table)
  k_gemm<4,1,256><<<dim3(2, (NV + 127) / 128), 256, 0, stream>>>(
      value, WTval, bval, nullptr, vprj_bf, nullptr, nullptr, NV, 256);

  // deformable sampling -> smp(bf16)
  k_sample<<<NQ * NHEAD / 4, 256, 0, stream>>>(vprjG, idxA, wA, smp_bf);

  // out proj + residuals -> x (d_out)
  k_gemm<2,0,256><<<dim3(2, (NQ + 127) / 128), 256, 0, stream>>>(
      smp_bf, WTout, bout, out, nullptr, query, iden, NQ, 256);

  // LN2 -> h(bf16)
  k_ln2<<<NQ / 4, 256, 0, stream>>>(out, n2g, n2b, h_bf);

  // FFN1: gelu(h@W1+b1) -> mid(bf16)
  k_gemm<1,0,256><<<dim3(8, (NQ + 127) / 128), 256, 0, stream>>>(
      h_bf, WT1, b1, nullptr, mid_bf, nullptr, nullptr, NQ, 1024);

  // FFN2: x += mid@W2+b2 (in place on d_out)
  k_gemm<3,0,1024><<<dim3(2, (NQ + 127) / 128), 256, 0, stream>>>(
      mid_bf, WT2, b2, out, nullptr, nullptr, nullptr, NQ, 256);
}

// Round 11
// 379.290 us; speedup vs baseline: 1.5158x; 1.1685x over previous
//
#include <hip/hip_runtime.h>
#include <hip/hip_bf16.h>
#include <math.h>

#define NQ 40000
#define NV 52500
#define D 256
#define NHEAD 8
#define HD 32
#define GUARD 256   // guard rows around vproj table (clamp-free sampling)

using bf16x8 = __attribute__((ext_vector_type(8))) short;
using f32x4  = __attribute__((ext_vector_type(4))) float;
typedef int v2i32 __attribute__((ext_vector_type(2)));

__device__ __forceinline__ short f2bf(float f) {
  union { __hip_bfloat16 h; short s; } u;
  u.h = __float2bfloat16(f);
  return u.s;
}
__device__ __forceinline__ float bf2f(unsigned short s) {
  return __uint_as_float((unsigned)s << 16);
}
__device__ __forceinline__ unsigned pack2(float lo, float hi) {
  return (unsigned)(unsigned short)f2bf(lo) |
         ((unsigned)(unsigned short)f2bf(hi) << 16);
}
// async global->LDS, 16B per lane, wave-uniform LDS base
__device__ __forceinline__ void gload16(const void* g, void* l) {
  __builtin_amdgcn_global_load_lds(
      (const __attribute__((address_space(1))) unsigned int*)g,
      (__attribute__((address_space(3))) unsigned int*)l, 16, 0, 0);
}

// cross-lane sum helpers: x + x[lane^K]
template<int IMM>
__device__ __forceinline__ float swz_add(float x) {   // K = 4 or 8 (ds pipe)
  return x + __int_as_float(__builtin_amdgcn_ds_swizzle(__float_as_int(x), IMM));
}
__device__ __forceinline__ float xor16_add(float x) {
#if __has_builtin(__builtin_amdgcn_permlane16_swap)
  v2i32 r = __builtin_amdgcn_permlane16_swap(__float_as_int(x), __float_as_int(x), false, false);
  return __int_as_float(r[0]) + __int_as_float(r[1]);
#else
  return x + __shfl_xor(x, 16);
#endif
}
__device__ __forceinline__ float xor32_add(float x) {
#if __has_builtin(__builtin_amdgcn_permlane32_swap)
  v2i32 r = __builtin_amdgcn_permlane32_swap(__float_as_int(x), __float_as_int(x), false, false);
  return __int_as_float(r[0]) + __int_as_float(r[1]);
#else
  return x + __shfl_xor(x, 32);
#endif
}

// ---------------------------------------------------- weight transpose->bf16
__global__ __launch_bounds__(256) void k_wt(const float* __restrict__ Wm,
                                            short* __restrict__ WT, int K, int N) {
  int idx = blockIdx.x * 256 + threadIdx.x;
  if (idx >= N * K) return;
  int n = idx / K, k = idx - n * K;
  WT[idx] = f2bf(Wm[(size_t)k * N + n]);
}

__global__ void k_catbias(const float* __restrict__ a, const float* __restrict__ b,
                          float* __restrict__ o) {
  int i = threadIdx.x;
  if (i < 192) o[i] = a[i];
  else if (i < 288) o[i] = b[i - 192];
}

// ---------------------------------------------------------------- LN1 + qp
__global__ __launch_bounds__(256) void k_ln1(const float* __restrict__ qin,
                                             const float* __restrict__ qpos,
                                             const float* __restrict__ g,
                                             const float* __restrict__ b,
                                             float* __restrict__ id_out,
                                             short* __restrict__ qp_out) {
  int wave = threadIdx.x >> 6;
  int lane = threadIdx.x & 63;
  int row  = blockIdx.x * 4 + wave;
  float4 x = ((const float4*)(qin + (size_t)row * D))[lane];
  float s  = x.x + x.y + x.z + x.w;
  float ss = x.x*x.x + x.y*x.y + x.z*x.z + x.w*x.w;
  for (int o = 32; o > 0; o >>= 1) { s += __shfl_down(s, o); ss += __shfl_down(ss, o); }
  s  = __shfl(s, 0);
  ss = __shfl(ss, 0);
  float m   = s * (1.0f / 256.0f);
  float var = ss * (1.0f / 256.0f) - m * m;
  float rs  = rsqrtf(var + 1e-5f);
  float4 gg = ((const float4*)g)[lane];
  float4 bb = ((const float4*)b)[lane];
  float4 qn;
  qn.x = (x.x - m) * rs * gg.x + bb.x;
  qn.y = (x.y - m) * rs * gg.y + bb.y;
  qn.z = (x.z - m) * rs * gg.z + bb.z;
  qn.w = (x.w - m) * rs * gg.w + bb.w;
  ((float4*)(id_out + (size_t)row * D))[lane] = qn;
  float4 p = ((const float4*)(qpos + (size_t)row * D))[lane];
  short4 o;
  o.x = f2bf(qn.x + p.x); o.y = f2bf(qn.y + p.y);
  o.z = f2bf(qn.z + p.z); o.w = f2bf(qn.w + p.w);
  ((short4*)(qp_out + (size_t)row * D))[lane] = o;
}

// ----------------------------------------------------------- LN2 -> bf16 h
__global__ __launch_bounds__(256) void k_ln2(const float* __restrict__ xin,
                                             const float* __restrict__ g,
                                             const float* __restrict__ b,
                                             short* __restrict__ h_out) {
  int wave = threadIdx.x >> 6;
  int lane = threadIdx.x & 63;
  int row  = blockIdx.x * 4 + wave;
  float4 x = ((const float4*)(xin + (size_t)row * D))[lane];
  float s  = x.x + x.y + x.z + x.w;
  float ss = x.x*x.x + x.y*x.y + x.z*x.z + x.w*x.w;
  for (int o = 32; o > 0; o >>= 1) { s += __shfl_down(s, o); ss += __shfl_down(ss, o); }
  s  = __shfl(s, 0);
  ss = __shfl(ss, 0);
  float m   = s * (1.0f / 256.0f);
  float var = ss * (1.0f / 256.0f) - m * m;
  float rs  = rsqrtf(var + 1e-5f);
  float4 gg = ((const float4*)g)[lane];
  float4 bb = ((const float4*)b)[lane];
  short4 o;
  o.x = f2bf((x.x - m) * rs * gg.x + bb.x);
  o.y = f2bf((x.y - m) * rs * gg.y + bb.y);
  o.z = f2bf((x.z - m) * rs * gg.z + bb.z);
  o.w = f2bf((x.w - m) * rs * gg.w + bb.w);
  ((short4*)(h_out + (size_t)row * D))[lane] = o;
}

// --------------------------------------------------------------- MFMA GEMM
// 128x128 tile, BK=32, triple-buffered LDS, depth-2 counted-vmcnt pipeline.
// Epilogue: LDS-repack (4 chunks of 32x128 f32, pad-140) -> coalesced
// dwordx4 loads/stores; kills the 64-scalar-store epilogue.
// EPI: 0 = store f32; 1 = gelu -> bf16; 2 = + R1 + R2 -> f32; 3 = Cf += v;
//      4 = store bf16
template<int EPI, int CVTA, int K>
__global__ __launch_bounds__(256) void k_gemm(const void* __restrict__ Ain,
                                              const short* __restrict__ WT,
                                              const float* __restrict__ bias,
                                              float* __restrict__ Cf,
                                              short* __restrict__ Cb,
                                              const float* __restrict__ R1,
                                              const float* __restrict__ R2,
                                              int M, int N) {
  constexpr int NT = K / 32;
  __shared__ short Al[3][4096];
  __shared__ short Bl[3][4096];
  const int tid = threadIdx.x;

  // XCD-chunked bijective block swizzle (T1)
  const int nbx = gridDim.x;
  const int nwg = nbx * gridDim.y;
  int flat = blockIdx.y * nbx + blockIdx.x;
  {
    int xcd = flat & 7, pos = flat >> 3;
    int qq = nwg >> 3, rr = nwg & 7;
    flat = (xcd < rr ? xcd * (qq + 1) : rr * (qq + 1) + (xcd - rr) * qq) + pos;
  }
  const int n0 = (flat % nbx) * 128, m0 = (flat / nbx) * 128;

  const int w = tid >> 6, l = tid & 63;
  const int wm = (w >> 1) * 64, wn = (w & 1) * 64;
  const int lr = l & 15;

  const int c0s = w * 2, c1s = c0s + 1;
  const int sr = l >> 2;
  const int sg = (((l & 3) ^ ((l >> 3) & 3)) << 3);   // swizzled src slot
  const int ar0 = min(m0 + c0s * 16 + sr, M - 1);
  const int ar1 = min(m0 + c1s * 16 + sr, M - 1);
  const int br0 = min(n0 + c0s * 16 + sr, N - 1);
  const int br1 = min(n0 + c1s * 16 + sr, N - 1);
  const short* bP0 = WT + (size_t)br0 * K + sg;
  const short* bP1 = WT + (size_t)br1 * K + sg;
  const short* aP0 = (const short*)Ain + (size_t)ar0 * K + sg;
  const short* aP1 = (const short*)Ain + (size_t)ar1 * K + sg;
  const float* aF0 = (const float*)Ain + (size_t)ar0 * K + sg;
  const float* aF1 = (const float*)Ain + (size_t)ar1 * K + sg;
  short* wD0 = &Al[0][(c0s * 16 + sr) * 32 + ((l & 3) << 3)];
  short* wD1 = &Al[0][(c1s * 16 + sr) * 32 + ((l & 3) << 3)];

  const int fsw = (((l >> 4) ^ ((l >> 1) & 3)) << 3);  // swizzled read slot
  const int aRd = (wm + lr) * 32 + fsw;
  const int bRd = (wn + lr) * 32 + fsw;

  f32x4 acc[4][4];
#pragma unroll
  for (int i = 0; i < 4; ++i)
#pragma unroll
    for (int j = 0; j < 4; ++j) acc[i][j] = (f32x4){0, 0, 0, 0};

  if (CVTA) {
    // ---------------- 2-phase reg-staged cvt path ------------------------
    {
      float4 f00 = *(const float4*)(aF0);
      float4 f01 = *(const float4*)(aF0 + 4);
      float4 f10 = *(const float4*)(aF1);
      float4 f11 = *(const float4*)(aF1 + 4);
      int4 p0, p1;
      p0.x = pack2(f00.x, f00.y); p0.y = pack2(f00.z, f00.w);
      p0.z = pack2(f01.x, f01.y); p0.w = pack2(f01.z, f01.w);
      p1.x = pack2(f10.x, f10.y); p1.y = pack2(f10.z, f10.w);
      p1.z = pack2(f11.x, f11.y); p1.w = pack2(f11.z, f11.w);
      *(int4*)wD0 = p0;
      *(int4*)wD1 = p1;
      gload16(bP0, &Bl[0][c0s * 512]);
      gload16(bP1, &Bl[0][c1s * 512]);
      __syncthreads();
    }
#pragma unroll 2
    for (int t = 0; t < NT - 1; ++t) {
      const int buf = t & 1, nbuf = buf ^ 1;
      const int kn = (t + 1) * 32;
      float4 f00 = *(const float4*)(aF0 + kn);
      float4 f01 = *(const float4*)(aF0 + kn + 4);
      float4 f10 = *(const float4*)(aF1 + kn);
      float4 f11 = *(const float4*)(aF1 + kn + 4);
      gload16(bP0 + kn, &Bl[nbuf][c0s * 512]);
      gload16(bP1 + kn, &Bl[nbuf][c1s * 512]);

      bf16x8 af[4], bfr[4];
#pragma unroll
      for (int i = 0; i < 4; ++i) {
        af[i]  = *(const bf16x8*)&Al[buf][aRd + i * 512];
        bfr[i] = *(const bf16x8*)&Bl[buf][bRd + i * 512];
      }
#pragma unroll
      for (int i = 0; i < 4; ++i)
#pragma unroll
        for (int j = 0; j < 4; ++j)
          acc[i][j] = __builtin_amdgcn_mfma_f32_16x16x32_bf16(af[i], bfr[j], acc[i][j], 0, 0, 0);

      int4 p0, p1;
      p0.x = pack2(f00.x, f00.y); p0.y = pack2(f00.z, f00.w);
      p0.z = pack2(f01.x, f01.y); p0.w = pack2(f01.z, f01.w);
      p1.x = pack2(f10.x, f10.y); p1.y = pack2(f10.z, f10.w);
      p1.z = pack2(f11.x, f11.y); p1.w = pack2(f11.z, f11.w);
      *(int4*)(wD0 + nbuf * 4096) = p0;
      *(int4*)(wD1 + nbuf * 4096) = p1;
      __syncthreads();
    }
    {
      const int buf = (NT - 1) & 1;
      bf16x8 af[4], bfr[4];
#pragma unroll
      for (int i = 0; i < 4; ++i) {
        af[i]  = *(const bf16x8*)&Al[buf][aRd + i * 512];
        bfr[i] = *(const bf16x8*)&Bl[buf][bRd + i * 512];
      }
#pragma unroll
      for (int i = 0; i < 4; ++i)
#pragma unroll
        for (int j = 0; j < 4; ++j)
          acc[i][j] = __builtin_amdgcn_mfma_f32_16x16x32_bf16(af[i], bfr[j], acc[i][j], 0, 0, 0);
    }
  } else {
    // ---------------- depth-2 counted-vmcnt pipeline, 3 buffers ----------
    gload16(aP0, &Al[0][c0s * 512]);
    gload16(aP1, &Al[0][c1s * 512]);
    gload16(bP0, &Bl[0][c0s * 512]);
    gload16(bP1, &Bl[0][c1s * 512]);
    if (NT > 1) {
      gload16(aP0 + 32, &Al[1][c0s * 512]);
      gload16(aP1 + 32, &Al[1][c1s * 512]);
      gload16(bP0 + 32, &Bl[1][c0s * 512]);
      gload16(bP1 + 32, &Bl[1][c1s * 512]);
    }
#pragma unroll
    for (int t = 0; t < NT; ++t) {
      const int buf = t % 3;
      if (t + 1 < NT) asm volatile("s_waitcnt vmcnt(4)" ::: "memory");
      else            asm volatile("s_waitcnt vmcnt(0)" ::: "memory");
      __builtin_amdgcn_s_barrier();
      __builtin_amdgcn_sched_barrier(0);
      if (t + 2 < NT) {
        const int kn = (t + 2) * 32, nb = (t + 2) % 3;
        gload16(aP0 + kn, &Al[nb][c0s * 512]);
        gload16(aP1 + kn, &Al[nb][c1s * 512]);
        gload16(bP0 + kn, &Bl[nb][c0s * 512]);
        gload16(bP1 + kn, &Bl[nb][c1s * 512]);
      }
      bf16x8 af[4], bfr[4];
#pragma unroll
      for (int i = 0; i < 4; ++i) {
        af[i]  = *(const bf16x8*)&Al[buf][aRd + i * 512];
        bfr[i] = *(const bf16x8*)&Bl[buf][bRd + i * 512];
      }
#pragma unroll
      for (int i = 0; i < 4; ++i)
#pragma unroll
        for (int j = 0; j < 4; ++j)
          acc[i][j] = __builtin_amdgcn_mfma_f32_16x16x32_bf16(af[i], bfr[j], acc[i][j], 0, 0, 0);
    }
  }

  // ---------------- epilogue: LDS-repacked coalesced I/O -------------------
  __syncthreads();                        // all K-loop LDS reads complete
  float* scratch = (float*)&Al[0][0];     // 32 x 140 f32 = 17.9 KB (< 24 KB)
  const int wrow = (w >> 1) * 16;
  const int rl2 = tid >> 3;               // 0..31 chunk-local row
  const int cc0 = (tid & 7) * 16;         // 0..112 col base
  const bool colok = (n0 + cc0) < N;
  float bsv[16];
#pragma unroll
  for (int c = 0; c < 4; ++c) {
    float4 bv = {0, 0, 0, 0};
    if (colok) bv = *(const float4*)&bias[n0 + cc0 + c * 4];
    bsv[c*4+0] = bv.x; bsv[c*4+1] = bv.y; bsv[c*4+2] = bv.z; bsv[c*4+3] = bv.w;
  }
#pragma unroll
  for (int i = 0; i < 4; ++i) {
#pragma unroll
    for (int j = 0; j < 4; ++j) {
      const int col = wn + j * 16 + (l & 15);
      const int rbase = wrow + ((l >> 4) << 2);
#pragma unroll
      for (int r = 0; r < 4; ++r)
        scratch[(rbase + r) * 140 + col] = acc[i][j][r];
    }
    __syncthreads();
    const int grow = m0 + 16 * i + (rl2 < 16 ? rl2 : 48 + rl2);
    if (colok && grow < M) {
      const size_t base = (size_t)grow * N + n0 + cc0;
      float v16[16];
#pragma unroll
      for (int c = 0; c < 4; ++c) {
        float4 vv = *(const float4*)&scratch[rl2 * 140 + cc0 + c * 4];
        v16[c*4+0] = vv.x + bsv[c*4+0];
        v16[c*4+1] = vv.y + bsv[c*4+1];
        v16[c*4+2] = vv.z + bsv[c*4+2];
        v16[c*4+3] = vv.w + bsv[c*4+3];
      }
      if (EPI == 0) {
#pragma unroll
        for (int c = 0; c < 4; ++c)
          *(float4*)&Cf[base + c * 4] =
              (float4){v16[c*4], v16[c*4+1], v16[c*4+2], v16[c*4+3]};
      } else if (EPI == 1) {
        uint4 o0, o1;
        unsigned pk[8];
#pragma unroll
        for (int c = 0; c < 8; ++c) {
          float a0 = v16[2*c], a1 = v16[2*c+1];
          // gelu = v * sigmoid-form of tanh approx: v*(1 - 1/(1+2^(u)))
          float u0 = a0 * (2.3021178f + 0.1029445f * a0 * a0);
          float u1 = a1 * (2.3021178f + 0.1029445f * a1 * a1);
          float g0 = a0 - a0 / (1.0f + exp2f(u0));
          float g1 = a1 - a1 / (1.0f + exp2f(u1));
          pk[c] = pack2(g0, g1);
        }
        o0 = (uint4){pk[0], pk[1], pk[2], pk[3]};
        o1 = (uint4){pk[4], pk[5], pk[6], pk[7]};
        *(uint4*)&Cb[base] = o0;
        *(uint4*)&Cb[base + 8] = o1;
      } else if (EPI == 2) {
#pragma unroll
        for (int c = 0; c < 4; ++c) {
          float4 r1 = *(const float4*)&R1[base + c * 4];
          float4 r2 = *(const float4*)&R2[base + c * 4];
          *(float4*)&Cf[base + c * 4] =
              (float4){v16[c*4] + r1.x + r2.x, v16[c*4+1] + r1.y + r2.y,
                       v16[c*4+2] + r1.z + r2.z, v16[c*4+3] + r1.w + r2.w};
        }
      } else if (EPI == 3) {
#pragma unroll
        for (int c = 0; c < 4; ++c) {
          float4 cur = *(const float4*)&Cf[base + c * 4];
          *(float4*)&Cf[base + c * 4] =
              (float4){cur.x + v16[c*4], cur.y + v16[c*4+1],
                       cur.z + v16[c*4+2], cur.w + v16[c*4+3]};
        }
      } else {
        uint4 o0 = (uint4){pack2(v16[0], v16[1]), pack2(v16[2], v16[3]),
                           pack2(v16[4], v16[5]), pack2(v16[6], v16[7])};
        uint4 o1 = (uint4){pack2(v16[8], v16[9]), pack2(v16[10], v16[11]),
                           pack2(v16[12], v16[13]), pack2(v16[14], v16[15])};
        *(uint4*)&Cb[base] = o0;
        *(uint4*)&Cb[base + 8] = o1;
      }
    }
    __syncthreads();
  }
}

// -------- softmax + per-point sampling meta (reads bf16 res): idx0 + 4 wgts
__global__ __launch_bounds__(256) void k_post(const unsigned short* __restrict__ res,
                                              const float* __restrict__ refp,
                                              int* __restrict__ idxA,
                                              unsigned short* __restrict__ wA) {
  int t = blockIdx.x * 256 + threadIdx.x;
  if (t >= NQ * 8) return;
  int q = t >> 3, h = t & 7;
  const unsigned short* rr = res + (size_t)q * 288;
  const unsigned short* lg = rr + 192 + h * 12;
  float lf[12];
#pragma unroll
  for (int i = 0; i < 12; ++i) lf[i] = bf2f(lg[i]);
  float mx = lf[0];
#pragma unroll
  for (int i = 1; i < 12; ++i) mx = fmaxf(mx, lf[i]);
  float e[12]; float sum = 0.0f;
#pragma unroll
  for (int i = 0; i < 12; ++i) { e[i] = expf(lf[i] - mx); sum += e[i]; }
  float inv = 1.0f / sum;

  const float dims[3] = {200.0f, 100.0f, 50.0f};
  const int   sts[3]  = {0, 40000, 50000};
#pragma unroll
  for (int l = 0; l < 3; ++l) {
    const int W = (int)dims[l];
    const float fW = dims[l];
    float rx = refp[((size_t)q * 3 + l) * 2 + 0];
    float ry = refp[((size_t)q * 3 + l) * 2 + 1];
    float invd = 1.0f / fW;
#pragma unroll
    for (int p = 0; p < 4; ++p) {
      int j = ((h * 3 + l) * 4 + p) * 2;
      float lx = rx + bf2f(rr[j + 0]) * invd;
      float ly = ry + bf2f(rr[j + 1]) * invd;
      float fx = lx * fW - 0.5f;
      float fy = ly * fW - 0.5f;
      float x0f = floorf(fx), y0f = floorf(fy);
      float tx = fx - x0f, ty = fy - y0f;
      int x0 = (int)x0f, y0 = (int)y0f;
      bool vx0 = (unsigned)x0       < (unsigned)W;
      bool vx1 = (unsigned)(x0 + 1) < (unsigned)W;
      bool vy0 = (unsigned)y0       < (unsigned)W;
      bool vy1 = (unsigned)(y0 + 1) < (unsigned)W;
      float a = e[l * 4 + p] * inv;
      float w00 = (vx0 && vy0) ? a * (1.0f - tx) * (1.0f - ty) : 0.0f;
      float w01 = (vx1 && vy0) ? a * tx * (1.0f - ty) : 0.0f;
      float w10 = (vx0 && vy1) ? a * (1.0f - tx) * ty : 0.0f;
      float w11 = (vx1 && vy1) ? a * tx * ty : 0.0f;
      int pidx = t * 12 + l * 4 + p;
      idxA[pidx] = sts[l] + y0 * W + x0;
      short4 wpk;
      wpk.x = f2bf(w00); wpk.y = f2bf(w01);
      wpk.z = f2bf(w10); wpk.w = f2bf(w11);
      *(short4*)(wA + (size_t)pidx * 4) = wpk;
    }
  }
}

// ----------------------------------------------------------- deform sampling
__global__ __launch_bounds__(256) void k_sample(const short* __restrict__ vprojG,
                                                const int* __restrict__ idxA,
                                                const unsigned short* __restrict__ wA,
                                                short* __restrict__ smp) {
  const int lane = threadIdx.x & 63;
  const int qh   = blockIdx.x * 4 + (threadIdx.x >> 6);
  const int h = qh & 7;
  const int pg  = lane >> 4;         // point in level
  const int tap = (lane >> 2) & 3;   // dy,dx
  const int cq  = lane & 3;          // channel oct (8 ch)
  const int dy = tap >> 1, dx = tap & 1;
  const short* vb = vprojG + (size_t)GUARD * D + h * HD + cq * 8;

  float acc[8];
#pragma unroll
  for (int j = 0; j < 8; ++j) acc[j] = 0.0f;

  const int Dim[3] = {200, 100, 50};
#pragma unroll
  for (int l = 0; l < 3; ++l) {
    const int W = Dim[l];
    const int tapoff = dy * W + dx;
    int pidx = qh * 12 + l * 4 + pg;
    int idx = idxA[pidx] + tapoff;
    float wgt = __uint_as_float((unsigned)wA[(size_t)pidx * 4 + tap] << 16);
    uint4 v = *(const uint4*)(vb + (ptrdiff_t)idx * D);
    acc[0] = fmaf(wgt, __uint_as_float(v.x << 16),        acc[0]);
    acc[1] = fmaf(wgt, __uint_as_float(v.x & 0xffff0000u), acc[1]);
    acc[2] = fmaf(wgt, __uint_as_float(v.y << 16),        acc[2]);
    acc[3] = fmaf(wgt, __uint_as_float(v.y & 0xffff0000u), acc[3]);
    acc[4] = fmaf(wgt, __uint_as_float(v.z << 16),        acc[4]);
    acc[5] = fmaf(wgt, __uint_as_float(v.z & 0xffff0000u), acc[5]);
    acc[6] = fmaf(wgt, __uint_as_float(v.w << 16),        acc[6]);
    acc[7] = fmaf(wgt, __uint_as_float(v.w & 0xffff0000u), acc[7]);
  }

#pragma unroll
  for (int j = 0; j < 8; ++j) {
    float a = swz_add<0x101F>(acc[j]);   // ^4
    a = swz_add<0x201F>(a);              // ^8
    a = xor16_add(a);                    // ^16
    acc[j] = xor32_add(a);               // ^32
  }

  if (lane < 4) {
    uint4 o;
    o.x = pack2(acc[0], acc[1]);
    o.y = pack2(acc[2], acc[3]);
    o.z = pack2(acc[4], acc[5]);
    o.w = pack2(acc[6], acc[7]);
    *(uint4*)(smp + (size_t)qh * HD + cq * 8) = o;
  }
}

// ---------------------------------------------------------------------------
extern "C" void kernel_launch(void* const* d_in, const int* in_sizes, int n_in,
                              void* d_out, int out_size, void* d_ws, size_t ws_size,
                              hipStream_t stream) {
  const float* query  = (const float*)d_in[0];
  const float* value  = (const float*)d_in[1];
  const float* qpos   = (const float*)d_in[2];
  const float* refp   = (const float*)d_in[3];
  const float* n1g = (const float*)d_in[6];
  const float* n1b = (const float*)d_in[7];
  const float* Woff = (const float*)d_in[8];
  const float* boff = (const float*)d_in[9];
  const float* Wattn = (const float*)d_in[10];
  const float* battn = (const float*)d_in[11];
  const float* Wval = (const float*)d_in[12];
  const float* bval = (const float*)d_in[13];
  const float* Wout = (const float*)d_in[14];
  const float* bout = (const float*)d_in[15];
  const float* n2g = (const float*)d_in[16];
  const float* n2b = (const float*)d_in[17];
  const float* W1 = (const float*)d_in[18];
  const float* b1 = (const float*)d_in[19];
  const float* W2 = (const float*)d_in[20];
  const float* b2 = (const float*)d_in[21];

  float* out = (float*)d_out;
  char* Wb = (char*)d_ws;

  // workspace layout (time-overlaid; ~156.6 MB total)
  short* qp_bf   = (short*)Wb;                    // [0,20.48M)   ln1 -> gemm288
  float* iden    = (float*)(Wb + 20480000);       // [20.48M,61.44M) ln1 -> outproj
  int*   idxA    = (int*)(Wb + 61440000);         // [61.44M,76.8M)  post -> sample
  unsigned short* wA = (unsigned short*)(Wb + 76800000); // [76.8M,107.52M)
  short* res_bf  = (short*)(Wb + 107520000);      // 23.04MB  gemm288 -> post
  short* vprjG   = (short*)(Wb + 107520000);      // guard+26.88MB+guard -> sample
  short* vprj_bf = (short*)(Wb + 107520000 + GUARD * D * 2); // table start
  short* h_bf    = (short*)(Wb + 107520000);      // 20.48MB  ln2 -> ffn1
  short* smp_bf  = (short*)(Wb + 134662144);      // 20.48MB  sample -> outproj
  short* mid_bf  = (short*)Wb;                    // [0,81.92M) ffn1 -> ffn2
  char*  Wbase   = Wb + 155142144;
  short* WT288   = (short*)(Wbase);
  short* WTval   = (short*)(Wbase + 147456);
  short* WTout   = (short*)(Wbase + 278528);
  short* WT1     = (short*)(Wbase + 409600);
  short* WT2     = (short*)(Wbase + 933888);
  float* bias288 = (float*)(Wbase + 1458176);

  // weight prep
  k_wt<<<(192 * 256 + 255) / 256, 256, 0, stream>>>(Woff, WT288, 256, 192);
  k_wt<<<(96 * 256 + 255) / 256, 256, 0, stream>>>(Wattn, WT288 + 192 * 256, 256, 96);
  k_wt<<<(256 * 256 + 255) / 256, 256, 0, stream>>>(Wval, WTval, 256, 256);
  k_wt<<<(256 * 256 + 255) / 256, 256, 0, stream>>>(Wout, WTout, 256, 256);
  k_wt<<<(1024 * 256 + 255) / 256, 256, 0, stream>>>(W1, WT1, 256, 1024);
  k_wt<<<(256 * 1024 + 255) / 256, 256, 0, stream>>>(W2, WT2, 1024, 256);
  k_catbias<<<1, 320, 0, stream>>>(boff, battn, bias288);

  // LN1 -> iden(f32), qp(bf16)
  k_ln1<<<NQ / 4, 256, 0, stream>>>(query, qpos, n1g, n1b, iden, qp_bf);

  // offsets+attn logits GEMM (N=288) -> bf16 res
  k_gemm<4,0,256><<<dim3(3, (NQ + 127) / 128), 256, 0, stream>>>(
      qp_bf, WT288, bias288, nullptr, res_bf, nullptr, nullptr, NQ, 288);
  // softmax + sampling meta
  k_post<<<(NQ * 8 + 255) / 256, 256, 0, stream>>>(
      (const unsigned short*)res_bf, refp, idxA, wA);

  // value proj (fused f32->bf16 A staging) -> bf16 (guard-padded table)
  k_gemm<4,1,256><<<dim3(2, (NV + 127) / 128), 256, 0, stream>>>(
      value, WTval, bval, nullptr, vprj_bf, nullptr, nullptr, NV, 256);

  // deformable sampling -> smp(bf16)
  k_sample<<<NQ * NHEAD / 4, 256, 0, stream>>>(vprjG, idxA, wA, smp_bf);

  // out proj + residuals -> x (d_out)
  k_gemm<2,0,256><<<dim3(2, (NQ + 127) / 128), 256, 0, stream>>>(
      smp_bf, WTout, bout, out, nullptr, query, iden, NQ, 256);

  // LN2 -> h(bf16)
  k_ln2<<<NQ / 4, 256, 0, stream>>>(out, n2g, n2b, h_bf);

  // FFN1: gelu(h@W1+b1) -> mid(bf16)
  k_gemm<1,0,256><<<dim3(8, (NQ + 127) / 128), 256, 0, stream>>>(
      h_bf, WT1, b1, nullptr, mid_bf, nullptr, nullptr, NQ, 1024);

  // FFN2: x += mid@W2+b2 (in place on d_out)
  k_gemm<3,0,1024><<<dim3(2, (NQ + 127) / 128), 256, 0, stream>>>(
      mid_bf, WT2, b2, out, nullptr, nullptr, nullptr, NQ, 256);
}

// Round 12
// 362.328 us; speedup vs baseline: 1.5868x; 1.0468x over previous
//
#include <hip/hip_runtime.h>
#include <hip/hip_bf16.h>
#include <math.h>

#define NQ 40000
#define NV 52500
#define D 256
#define NHEAD 8
#define HD 32
#define GUARD 256   // guard rows around vproj table (clamp-free sampling)

using bf16x8 = __attribute__((ext_vector_type(8))) short;
using f32x4  = __attribute__((ext_vector_type(4))) float;
typedef int v2i32 __attribute__((ext_vector_type(2)));

__device__ __forceinline__ short f2bf(float f) {
  union { __hip_bfloat16 h; short s; } u;
  u.h = __float2bfloat16(f);
  return u.s;
}
__device__ __forceinline__ float bf2f(unsigned short s) {
  return __uint_as_float((unsigned)s << 16);
}
__device__ __forceinline__ unsigned pack2(float lo, float hi) {
  return (unsigned)(unsigned short)f2bf(lo) |
         ((unsigned)(unsigned short)f2bf(hi) << 16);
}
// async global->LDS, 16B per lane, wave-uniform LDS base
__device__ __forceinline__ void gload16(const void* g, void* l) {
  __builtin_amdgcn_global_load_lds(
      (const __attribute__((address_space(1))) unsigned int*)g,
      (__attribute__((address_space(3))) unsigned int*)l, 16, 0, 0);
}

// cross-lane sum helpers: x + x[lane^K]
template<int IMM>
__device__ __forceinline__ float swz_add(float x) {   // K = 4 or 8 (ds pipe)
  return x + __int_as_float(__builtin_amdgcn_ds_swizzle(__float_as_int(x), IMM));
}

// ------------------------------------- all weight prep fused in one kernel
__global__ __launch_bounds__(256) void k_prep(const float* __restrict__ Woff,
                                              const float* __restrict__ Wattn,
                                              const float* __restrict__ Wval,
                                              const float* __restrict__ Wout,
                                              const float* __restrict__ W1,
                                              const float* __restrict__ W2,
                                              const float* __restrict__ boff,
                                              const float* __restrict__ battn,
                                              short* __restrict__ WT288,
                                              short* __restrict__ WTval,
                                              short* __restrict__ WTout,
                                              short* __restrict__ WT1,
                                              short* __restrict__ WT2,
                                              float* __restrict__ bias288) {
  int idx = blockIdx.x * 256 + threadIdx.x;
  if (idx < 49152) {                       // Woff^T  [192][256]
    int n = idx >> 8, k = idx & 255;
    WT288[idx] = f2bf(Woff[k * 192 + n]);
  } else if (idx < 73728) {                // Wattn^T [96][256]
    int li = idx - 49152; int n = li >> 8, k = li & 255;
    WT288[49152 + li] = f2bf(Wattn[k * 96 + n]);
  } else if (idx < 139264) {               // Wval^T [256][256]
    int li = idx - 73728; int n = li >> 8, k = li & 255;
    WTval[li] = f2bf(Wval[k * 256 + n]);
  } else if (idx < 204800) {               // Wout^T [256][256]
    int li = idx - 139264; int n = li >> 8, k = li & 255;
    WTout[li] = f2bf(Wout[k * 256 + n]);
  } else if (idx < 466944) {               // W1^T [1024][256]
    int li = idx - 204800; int n = li >> 8, k = li & 255;
    WT1[li] = f2bf(W1[k * 1024 + n]);
  } else if (idx < 729088) {               // W2^T [256][1024]
    int li = idx - 466944; int n = li >> 10, k = li & 1023;
    WT2[li] = f2bf(W2[k * 256 + n]);
  } else if (idx < 729376) {               // bias288
    int i = idx - 729088;
    bias288[i] = (i < 192) ? boff[i] : battn[i - 192];
  }
}

// ---------------------------------------------- LN1 + qp; iden stored bf16
__global__ __launch_bounds__(256) void k_ln1(const float* __restrict__ qin,
                                             const float* __restrict__ qpos,
                                             const float* __restrict__ g,
                                             const float* __restrict__ b,
                                             short* __restrict__ id_out,
                                             short* __restrict__ qp_out) {
  int wave = threadIdx.x >> 6;
  int lane = threadIdx.x & 63;
  int row  = blockIdx.x * 4 + wave;
  float4 x = ((const float4*)(qin + (size_t)row * D))[lane];
  float s  = x.x + x.y + x.z + x.w;
  float ss = x.x*x.x + x.y*x.y + x.z*x.z + x.w*x.w;
  for (int o = 32; o > 0; o >>= 1) { s += __shfl_down(s, o); ss += __shfl_down(ss, o); }
  s  = __shfl(s, 0);
  ss = __shfl(ss, 0);
  float m   = s * (1.0f / 256.0f);
  float var = ss * (1.0f / 256.0f) - m * m;
  float rs  = rsqrtf(var + 1e-5f);
  float4 gg = ((const float4*)g)[lane];
  float4 bb = ((const float4*)b)[lane];
  float4 qn;
  qn.x = (x.x - m) * rs * gg.x + bb.x;
  qn.y = (x.y - m) * rs * gg.y + bb.y;
  qn.z = (x.z - m) * rs * gg.z + bb.z;
  qn.w = (x.w - m) * rs * gg.w + bb.w;
  short4 io;
  io.x = f2bf(qn.x); io.y = f2bf(qn.y); io.z = f2bf(qn.z); io.w = f2bf(qn.w);
  ((short4*)(id_out + (size_t)row * D))[lane] = io;
  float4 p = ((const float4*)(qpos + (size_t)row * D))[lane];
  short4 o;
  o.x = f2bf(qn.x + p.x); o.y = f2bf(qn.y + p.y);
  o.z = f2bf(qn.z + p.z); o.w = f2bf(qn.w + p.w);
  ((short4*)(qp_out + (size_t)row * D))[lane] = o;
}

// ----------------------------------------------------------- LN2 -> bf16 h
__global__ __launch_bounds__(256) void k_ln2(const float* __restrict__ xin,
                                             const float* __restrict__ g,
                                             const float* __restrict__ b,
                                             short* __restrict__ h_out) {
  int wave = threadIdx.x >> 6;
  int lane = threadIdx.x & 63;
  int row  = blockIdx.x * 4 + wave;
  float4 x = ((const float4*)(xin + (size_t)row * D))[lane];
  float s  = x.x + x.y + x.z + x.w;
  float ss = x.x*x.x + x.y*x.y + x.z*x.z + x.w*x.w;
  for (int o = 32; o > 0; o >>= 1) { s += __shfl_down(s, o); ss += __shfl_down(ss, o); }
  s  = __shfl(s, 0);
  ss = __shfl(ss, 0);
  float m   = s * (1.0f / 256.0f);
  float var = ss * (1.0f / 256.0f) - m * m;
  float rs  = rsqrtf(var + 1e-5f);
  float4 gg = ((const float4*)g)[lane];
  float4 bb = ((const float4*)b)[lane];
  short4 o;
  o.x = f2bf((x.x - m) * rs * gg.x + bb.x);
  o.y = f2bf((x.y - m) * rs * gg.y + bb.y);
  o.z = f2bf((x.z - m) * rs * gg.z + bb.z);
  o.w = f2bf((x.w - m) * rs * gg.w + bb.w);
  ((short4*)(h_out + (size_t)row * D))[lane] = o;
}

// --------------------------------------------------------------- MFMA GEMM
// 128x128 tile, BK=32, triple-buffered LDS, depth-2 counted-vmcnt pipeline.
// LDS-repack epilogue with coalesced dwordx4 I/O.
// EPI: 0 = store f32; 1 = gelu -> bf16; 3 = Cf += v; 4 = store bf16;
//      5 = v + R1(f32) + R2(bf16) -> f32
template<int EPI, int CVTA, int K>
__global__ __launch_bounds__(256) void k_gemm(const void* __restrict__ Ain,
                                              const short* __restrict__ WT,
                                              const float* __restrict__ bias,
                                              float* __restrict__ Cf,
                                              short* __restrict__ Cb,
                                              const float* __restrict__ R1,
                                              const float* __restrict__ R2,
                                              int M, int N) {
  constexpr int NT = K / 32;
  __shared__ short Al[3][4096];
  __shared__ short Bl[3][4096];
  const int tid = threadIdx.x;

  // XCD-chunked bijective block swizzle (T1)
  const int nbx = gridDim.x;
  const int nwg = nbx * gridDim.y;
  int flat = blockIdx.y * nbx + blockIdx.x;
  {
    int xcd = flat & 7, pos = flat >> 3;
    int qq = nwg >> 3, rr = nwg & 7;
    flat = (xcd < rr ? xcd * (qq + 1) : rr * (qq + 1) + (xcd - rr) * qq) + pos;
  }
  const int n0 = (flat % nbx) * 128, m0 = (flat / nbx) * 128;

  const int w = tid >> 6, l = tid & 63;
  const int wm = (w >> 1) * 64, wn = (w & 1) * 64;
  const int lr = l & 15;

  const int c0s = w * 2, c1s = c0s + 1;
  const int sr = l >> 2;
  const int sg = (((l & 3) ^ ((l >> 3) & 3)) << 3);   // swizzled src slot
  const int ar0 = min(m0 + c0s * 16 + sr, M - 1);
  const int ar1 = min(m0 + c1s * 16 + sr, M - 1);
  const int br0 = min(n0 + c0s * 16 + sr, N - 1);
  const int br1 = min(n0 + c1s * 16 + sr, N - 1);
  const short* bP0 = WT + (size_t)br0 * K + sg;
  const short* bP1 = WT + (size_t)br1 * K + sg;
  const short* aP0 = (const short*)Ain + (size_t)ar0 * K + sg;
  const short* aP1 = (const short*)Ain + (size_t)ar1 * K + sg;
  const float* aF0 = (const float*)Ain + (size_t)ar0 * K + sg;
  const float* aF1 = (const float*)Ain + (size_t)ar1 * K + sg;
  short* wD0 = &Al[0][(c0s * 16 + sr) * 32 + ((l & 3) << 3)];
  short* wD1 = &Al[0][(c1s * 16 + sr) * 32 + ((l & 3) << 3)];

  const int fsw = (((l >> 4) ^ ((l >> 1) & 3)) << 3);  // swizzled read slot
  const int aRd = (wm + lr) * 32 + fsw;
  const int bRd = (wn + lr) * 32 + fsw;

  f32x4 acc[4][4];
#pragma unroll
  for (int i = 0; i < 4; ++i)
#pragma unroll
    for (int j = 0; j < 4; ++j) acc[i][j] = (f32x4){0, 0, 0, 0};

  if (CVTA) {
    // ---------------- 2-phase reg-staged cvt path ------------------------
    {
      float4 f00 = *(const float4*)(aF0);
      float4 f01 = *(const float4*)(aF0 + 4);
      float4 f10 = *(const float4*)(aF1);
      float4 f11 = *(const float4*)(aF1 + 4);
      int4 p0, p1;
      p0.x = pack2(f00.x, f00.y); p0.y = pack2(f00.z, f00.w);
      p0.z = pack2(f01.x, f01.y); p0.w = pack2(f01.z, f01.w);
      p1.x = pack2(f10.x, f10.y); p1.y = pack2(f10.z, f10.w);
      p1.z = pack2(f11.x, f11.y); p1.w = pack2(f11.z, f11.w);
      *(int4*)wD0 = p0;
      *(int4*)wD1 = p1;
      gload16(bP0, &Bl[0][c0s * 512]);
      gload16(bP1, &Bl[0][c1s * 512]);
      __syncthreads();
    }
#pragma unroll 2
    for (int t = 0; t < NT - 1; ++t) {
      const int buf = t & 1, nbuf = buf ^ 1;
      const int kn = (t + 1) * 32;
      float4 f00 = *(const float4*)(aF0 + kn);
      float4 f01 = *(const float4*)(aF0 + kn + 4);
      float4 f10 = *(const float4*)(aF1 + kn);
      float4 f11 = *(const float4*)(aF1 + kn + 4);
      gload16(bP0 + kn, &Bl[nbuf][c0s * 512]);
      gload16(bP1 + kn, &Bl[nbuf][c1s * 512]);

      bf16x8 af[4], bfr[4];
#pragma unroll
      for (int i = 0; i < 4; ++i) {
        af[i]  = *(const bf16x8*)&Al[buf][aRd + i * 512];
        bfr[i] = *(const bf16x8*)&Bl[buf][bRd + i * 512];
      }
#pragma unroll
      for (int i = 0; i < 4; ++i)
#pragma unroll
        for (int j = 0; j < 4; ++j)
          acc[i][j] = __builtin_amdgcn_mfma_f32_16x16x32_bf16(af[i], bfr[j], acc[i][j], 0, 0, 0);

      int4 p0, p1;
      p0.x = pack2(f00.x, f00.y); p0.y = pack2(f00.z, f00.w);
      p0.z = pack2(f01.x, f01.y); p0.w = pack2(f01.z, f01.w);
      p1.x = pack2(f10.x, f10.y); p1.y = pack2(f10.z, f10.w);
      p1.z = pack2(f11.x, f11.y); p1.w = pack2(f11.z, f11.w);
      *(int4*)(wD0 + nbuf * 4096) = p0;
      *(int4*)(wD1 + nbuf * 4096) = p1;
      __syncthreads();
    }
    {
      const int buf = (NT - 1) & 1;
      bf16x8 af[4], bfr[4];
#pragma unroll
      for (int i = 0; i < 4; ++i) {
        af[i]  = *(const bf16x8*)&Al[buf][aRd + i * 512];
        bfr[i] = *(const bf16x8*)&Bl[buf][bRd + i * 512];
      }
#pragma unroll
      for (int i = 0; i < 4; ++i)
#pragma unroll
        for (int j = 0; j < 4; ++j)
          acc[i][j] = __builtin_amdgcn_mfma_f32_16x16x32_bf16(af[i], bfr[j], acc[i][j], 0, 0, 0);
    }
  } else {
    // ---------------- depth-2 counted-vmcnt pipeline, 3 buffers ----------
    gload16(aP0, &Al[0][c0s * 512]);
    gload16(aP1, &Al[0][c1s * 512]);
    gload16(bP0, &Bl[0][c0s * 512]);
    gload16(bP1, &Bl[0][c1s * 512]);
    if (NT > 1) {
      gload16(aP0 + 32, &Al[1][c0s * 512]);
      gload16(aP1 + 32, &Al[1][c1s * 512]);
      gload16(bP0 + 32, &Bl[1][c0s * 512]);
      gload16(bP1 + 32, &Bl[1][c1s * 512]);
    }
#pragma unroll
    for (int t = 0; t < NT; ++t) {
      const int buf = t % 3;
      if (t + 1 < NT) asm volatile("s_waitcnt vmcnt(4)" ::: "memory");
      else            asm volatile("s_waitcnt vmcnt(0)" ::: "memory");
      __builtin_amdgcn_s_barrier();
      __builtin_amdgcn_sched_barrier(0);
      if (t + 2 < NT) {
        const int kn = (t + 2) * 32, nb = (t + 2) % 3;
        gload16(aP0 + kn, &Al[nb][c0s * 512]);
        gload16(aP1 + kn, &Al[nb][c1s * 512]);
        gload16(bP0 + kn, &Bl[nb][c0s * 512]);
        gload16(bP1 + kn, &Bl[nb][c1s * 512]);
      }
      bf16x8 af[4], bfr[4];
#pragma unroll
      for (int i = 0; i < 4; ++i) {
        af[i]  = *(const bf16x8*)&Al[buf][aRd + i * 512];
        bfr[i] = *(const bf16x8*)&Bl[buf][bRd + i * 512];
      }
#pragma unroll
      for (int i = 0; i < 4; ++i)
#pragma unroll
        for (int j = 0; j < 4; ++j)
          acc[i][j] = __builtin_amdgcn_mfma_f32_16x16x32_bf16(af[i], bfr[j], acc[i][j], 0, 0, 0);
    }
  }

  // ---------------- epilogue: LDS-repacked coalesced I/O -------------------
  __syncthreads();                        // all K-loop LDS reads complete
  float* scratch = (float*)&Al[0][0];     // 32 x 140 f32 = 17.9 KB
  const unsigned short* R2b = (const unsigned short*)R2;
  const int wrow = (w >> 1) * 16;
  const int rl2 = tid >> 3;               // 0..31 chunk-local row
  const int cc0 = (tid & 7) * 16;         // 0..112 col base
  const bool colok = (n0 + cc0) < N;
  float bsv[16];
#pragma unroll
  for (int c = 0; c < 4; ++c) {
    float4 bv = {0, 0, 0, 0};
    if (colok) bv = *(const float4*)&bias[n0 + cc0 + c * 4];
    bsv[c*4+0] = bv.x; bsv[c*4+1] = bv.y; bsv[c*4+2] = bv.z; bsv[c*4+3] = bv.w;
  }
#pragma unroll
  for (int i = 0; i < 4; ++i) {
#pragma unroll
    for (int j = 0; j < 4; ++j) {
      const int col = wn + j * 16 + (l & 15);
      const int rbase = wrow + ((l >> 4) << 2);
#pragma unroll
      for (int r = 0; r < 4; ++r)
        scratch[(rbase + r) * 140 + col] = acc[i][j][r];
    }
    __syncthreads();
    const int grow = m0 + 16 * i + (rl2 < 16 ? rl2 : 48 + rl2);
    if (colok && grow < M) {
      const size_t base = (size_t)grow * N + n0 + cc0;
      float v16[16];
#pragma unroll
      for (int c = 0; c < 4; ++c) {
        float4 vv = *(const float4*)&scratch[rl2 * 140 + cc0 + c * 4];
        v16[c*4+0] = vv.x + bsv[c*4+0];
        v16[c*4+1] = vv.y + bsv[c*4+1];
        v16[c*4+2] = vv.z + bsv[c*4+2];
        v16[c*4+3] = vv.w + bsv[c*4+3];
      }
      if (EPI == 0) {
#pragma unroll
        for (int c = 0; c < 4; ++c)
          *(float4*)&Cf[base + c * 4] =
              (float4){v16[c*4], v16[c*4+1], v16[c*4+2], v16[c*4+3]};
      } else if (EPI == 1) {
        unsigned pk[8];
#pragma unroll
        for (int c = 0; c < 8; ++c) {
          float a0 = v16[2*c], a1 = v16[2*c+1];
          float u0 = a0 * (2.3021178f + 0.1029445f * a0 * a0);
          float u1 = a1 * (2.3021178f + 0.1029445f * a1 * a1);
          float g0 = a0 - a0 / (1.0f + exp2f(u0));
          float g1 = a1 - a1 / (1.0f + exp2f(u1));
          pk[c] = pack2(g0, g1);
        }
        *(uint4*)&Cb[base] = (uint4){pk[0], pk[1], pk[2], pk[3]};
        *(uint4*)&Cb[base + 8] = (uint4){pk[4], pk[5], pk[6], pk[7]};
      } else if (EPI == 5) {
        uint4 rb0 = *(const uint4*)&R2b[base];
        uint4 rb1 = *(const uint4*)&R2b[base + 8];
        unsigned rw[8] = {rb0.x, rb0.y, rb0.z, rb0.w, rb1.x, rb1.y, rb1.z, rb1.w};
        float r2v[16];
#pragma unroll
        for (int c = 0; c < 8; ++c) {
          r2v[2*c]   = __uint_as_float(rw[c] << 16);
          r2v[2*c+1] = __uint_as_float(rw[c] & 0xffff0000u);
        }
#pragma unroll
        for (int c = 0; c < 4; ++c) {
          float4 r1 = *(const float4*)&R1[base + c * 4];
          *(float4*)&Cf[base + c * 4] =
              (float4){v16[c*4] + r1.x + r2v[c*4], v16[c*4+1] + r1.y + r2v[c*4+1],
                       v16[c*4+2] + r1.z + r2v[c*4+2], v16[c*4+3] + r1.w + r2v[c*4+3]};
        }
      } else if (EPI == 3) {
#pragma unroll
        for (int c = 0; c < 4; ++c) {
          float4 cur = *(const float4*)&Cf[base + c * 4];
          *(float4*)&Cf[base + c * 4] =
              (float4){cur.x + v16[c*4], cur.y + v16[c*4+1],
                       cur.z + v16[c*4+2], cur.w + v16[c*4+3]};
        }
      } else {
        uint4 o0 = (uint4){pack2(v16[0], v16[1]), pack2(v16[2], v16[3]),
                           pack2(v16[4], v16[5]), pack2(v16[6], v16[7])};
        uint4 o1 = (uint4){pack2(v16[8], v16[9]), pack2(v16[10], v16[11]),
                           pack2(v16[12], v16[13]), pack2(v16[14], v16[15])};
        *(uint4*)&Cb[base] = o0;
        *(uint4*)&Cb[base + 8] = o1;
      }
    }
    __syncthreads();
  }
}

// -------- softmax + per-point sampling meta (reads bf16 res): idx0 + 4 wgts
__global__ __launch_bounds__(256) void k_post(const unsigned short* __restrict__ res,
                                              const float* __restrict__ refp,
                                              int* __restrict__ idxA,
                                              unsigned short* __restrict__ wA) {
  int t = blockIdx.x * 256 + threadIdx.x;
  if (t >= NQ * 8) return;
  int q = t >> 3, h = t & 7;
  const unsigned short* rr = res + (size_t)q * 288;
  const unsigned short* lg = rr + 192 + h * 12;
  float lf[12];
#pragma unroll
  for (int i = 0; i < 12; ++i) lf[i] = bf2f(lg[i]);
  float mx = lf[0];
#pragma unroll
  for (int i = 1; i < 12; ++i) mx = fmaxf(mx, lf[i]);
  float e[12]; float sum = 0.0f;
#pragma unroll
  for (int i = 0; i < 12; ++i) { e[i] = expf(lf[i] - mx); sum += e[i]; }
  float inv = 1.0f / sum;

  const float dims[3] = {200.0f, 100.0f, 50.0f};
  const int   sts[3]  = {0, 40000, 50000};
#pragma unroll
  for (int l = 0; l < 3; ++l) {
    const int W = (int)dims[l];
    const float fW = dims[l];
    float rx = refp[((size_t)q * 3 + l) * 2 + 0];
    float ry = refp[((size_t)q * 3 + l) * 2 + 1];
    float invd = 1.0f / fW;
#pragma unroll
    for (int p = 0; p < 4; ++p) {
      int j = ((h * 3 + l) * 4 + p) * 2;
      float lx = rx + bf2f(rr[j + 0]) * invd;
      float ly = ry + bf2f(rr[j + 1]) * invd;
      float fx = lx * fW - 0.5f;
      float fy = ly * fW - 0.5f;
      float x0f = floorf(fx), y0f = floorf(fy);
      float tx = fx - x0f, ty = fy - y0f;
      int x0 = (int)x0f, y0 = (int)y0f;
      bool vx0 = (unsigned)x0       < (unsigned)W;
      bool vx1 = (unsigned)(x0 + 1) < (unsigned)W;
      bool vy0 = (unsigned)y0       < (unsigned)W;
      bool vy1 = (unsigned)(y0 + 1) < (unsigned)W;
      float a = e[l * 4 + p] * inv;
      float w00 = (vx0 && vy0) ? a * (1.0f - tx) * (1.0f - ty) : 0.0f;
      float w01 = (vx1 && vy0) ? a * tx * (1.0f - ty) : 0.0f;
      float w10 = (vx0 && vy1) ? a * (1.0f - tx) * ty : 0.0f;
      float w11 = (vx1 && vy1) ? a * tx * ty : 0.0f;
      int pidx = t * 12 + l * 4 + p;
      idxA[pidx] = sts[l] + y0 * W + x0;
      short4 wpk;
      wpk.x = f2bf(w00); wpk.y = f2bf(w01);
      wpk.z = f2bf(w10); wpk.w = f2bf(w11);
      *(short4*)(wA + (size_t)pidx * 4) = wpk;
    }
  }
}

// ----------------------------------------------------------- deform sampling
// One wave = 4 (q,h). lane = qh-slot(2b) | tap(2b) | cq(2b).
// 12 serialized points per qh-slot; reduction is tap-only (2 ds_swizzle
// levels); 16/64 lanes store fully-coalesced 4x64B.
__global__ __launch_bounds__(256) void k_sample(const short* __restrict__ vprojG,
                                                const int* __restrict__ idxA,
                                                const unsigned short* __restrict__ wA,
                                                short* __restrict__ smp) {
  const int lane = threadIdx.x & 63;
  const int qh   = blockIdx.x * 16 + (threadIdx.x >> 6) * 4 + (lane >> 4);
  const int tap  = (lane >> 2) & 3;  // dy,dx
  const int cq   = lane & 3;         // channel oct (8 ch)
  const int h = qh & 7;
  const int dy = tap >> 1, dx = tap & 1;
  const short* vb = vprojG + (size_t)GUARD * D + h * HD + cq * 8;
  const int pbase = qh * 12;

  float acc[8];
#pragma unroll
  for (int j = 0; j < 8; ++j) acc[j] = 0.0f;

  const int Dim[3] = {200, 100, 50};
#pragma unroll
  for (int it = 0; it < 12; ++it) {
    const int W = Dim[it >> 2];
    const int tapoff = dy * W + dx;
    int pidx = pbase + it;
    int idx = idxA[pidx] + tapoff;
    float wgt = bf2f(wA[(size_t)pidx * 4 + tap]);
    uint4 v = *(const uint4*)(vb + (ptrdiff_t)idx * D);
    acc[0] = fmaf(wgt, __uint_as_float(v.x << 16),        acc[0]);
    acc[1] = fmaf(wgt, __uint_as_float(v.x & 0xffff0000u), acc[1]);
    acc[2] = fmaf(wgt, __uint_as_float(v.y << 16),        acc[2]);
    acc[3] = fmaf(wgt, __uint_as_float(v.y & 0xffff0000u), acc[3]);
    acc[4] = fmaf(wgt, __uint_as_float(v.z << 16),        acc[4]);
    acc[5] = fmaf(wgt, __uint_as_float(v.z & 0xffff0000u), acc[5]);
    acc[6] = fmaf(wgt, __uint_as_float(v.w << 16),        acc[6]);
    acc[7] = fmaf(wgt, __uint_as_float(v.w & 0xffff0000u), acc[7]);
  }

  // tap reduce only (lane bits 2,3) — butterfly leaves sum in all lanes
#pragma unroll
  for (int j = 0; j < 8; ++j) {
    float a = swz_add<0x101F>(acc[j]);   // ^4
    acc[j] = swz_add<0x201F>(a);         // ^8
  }

  if (tap == 0) {
    uint4 o;
    o.x = pack2(acc[0], acc[1]);
    o.y = pack2(acc[2], acc[3]);
    o.z = pack2(acc[4], acc[5]);
    o.w = pack2(acc[6], acc[7]);
    *(uint4*)(smp + (size_t)qh * HD + cq * 8) = o;
  }
}

// ---------------------------------------------------------------------------
extern "C" void kernel_launch(void* const* d_in, const int* in_sizes, int n_in,
                              void* d_out, int out_size, void* d_ws, size_t ws_size,
                              hipStream_t stream) {
  const float* query  = (const float*)d_in[0];
  const float* value  = (const float*)d_in[1];
  const float* qpos   = (const float*)d_in[2];
  const float* refp   = (const float*)d_in[3];
  const float* n1g = (const float*)d_in[6];
  const float* n1b = (const float*)d_in[7];
  const float* Woff = (const float*)d_in[8];
  const float* boff = (const float*)d_in[9];
  const float* Wattn = (const float*)d_in[10];
  const float* battn = (const float*)d_in[11];
  const float* Wval = (const float*)d_in[12];
  const float* bval = (const float*)d_in[13];
  const float* Wout = (const float*)d_in[14];
  const float* bout = (const float*)d_in[15];
  const float* n2g = (const float*)d_in[16];
  const float* n2b = (const float*)d_in[17];
  const float* W1 = (const float*)d_in[18];
  const float* b1 = (const float*)d_in[19];
  const float* W2 = (const float*)d_in[20];
  const float* b2 = (const float*)d_in[21];

  float* out = (float*)d_out;
  char* Wb = (char*)d_ws;

  // workspace layout (time-overlaid; ~156.6 MB total)
  short* qp_bf   = (short*)Wb;                    // [0,20.48M)   ln1 -> gemm288
  short* iden_bf = (short*)(Wb + 20480000);       // 20.48MB  ln1 -> outproj
  int*   idxA    = (int*)(Wb + 61440000);         // [61.44M,76.8M)  post -> sample
  unsigned short* wA = (unsigned short*)(Wb + 76800000); // [76.8M,107.52M)
  short* res_bf  = (short*)(Wb + 107520000);      // 23.04MB  gemm288 -> post
  short* vprjG   = (short*)(Wb + 107520000);      // guard+26.88MB+guard -> sample
  short* vprj_bf = (short*)(Wb + 107520000 + GUARD * D * 2); // table start
  short* h_bf    = (short*)(Wb + 107520000);      // 20.48MB  ln2 -> ffn1
  short* smp_bf  = (short*)(Wb + 134662144);      // 20.48MB  sample -> outproj
  short* mid_bf  = (short*)Wb;                    // [0,81.92M) ffn1 -> ffn2
  char*  Wbase   = Wb + 155142144;
  short* WT288   = (short*)(Wbase);
  short* WTval   = (short*)(Wbase + 147456);
  short* WTout   = (short*)(Wbase + 278528);
  short* WT1     = (short*)(Wbase + 409600);
  short* WT2     = (short*)(Wbase + 933888);
  float* bias288 = (float*)(Wbase + 1458176);

  // weight prep (single fused kernel)
  k_prep<<<(729376 + 255) / 256, 256, 0, stream>>>(
      Woff, Wattn, Wval, Wout, W1, W2, boff, battn,
      WT288, WTval, WTout, WT1, WT2, bias288);

  // LN1 -> iden(bf16), qp(bf16)
  k_ln1<<<NQ / 4, 256, 0, stream>>>(query, qpos, n1g, n1b, iden_bf, qp_bf);

  // offsets+attn logits GEMM (N=288) -> bf16 res
  k_gemm<4,0,256><<<dim3(3, (NQ + 127) / 128), 256, 0, stream>>>(
      qp_bf, WT288, bias288, nullptr, res_bf, nullptr, nullptr, NQ, 288);
  // softmax + sampling meta
  k_post<<<(NQ * 8 + 255) / 256, 256, 0, stream>>>(
      (const unsigned short*)res_bf, refp, idxA, wA);

  // value proj (fused f32->bf16 A staging) -> bf16 (guard-padded table)
  k_gemm<4,1,256><<<dim3(2, (NV + 127) / 128), 256, 0, stream>>>(
      value, WTval, bval, nullptr, vprj_bf, nullptr, nullptr, NV, 256);

  // deformable sampling -> smp(bf16); 4 qh per wave, 16 per block
  k_sample<<<NQ * NHEAD / 16, 256, 0, stream>>>(vprjG, idxA, wA, smp_bf);

  // out proj + residuals (query f32 + iden bf16) -> x (d_out)
  k_gemm<5,0,256><<<dim3(2, (NQ + 127) / 128), 256, 0, stream>>>(
      smp_bf, WTout, bout, out, nullptr, query, (const float*)iden_bf, NQ, 256);

  // LN2 -> h(bf16)
  k_ln2<<<NQ / 4, 256, 0, stream>>>(out, n2g, n2b, h_bf);

  // FFN1: gelu(h@W1+b1) -> mid(bf16)
  k_gemm<1,0,256><<<dim3(8, (NQ + 127) / 128), 256, 0, stream>>>(
      h_bf, WT1, b1, nullptr, mid_bf, nullptr, nullptr, NQ, 1024);

  // FFN2: x += mid@W2+b2 (in place on d_out)
  k_gemm<3,0,1024><<<dim3(2, (NQ + 127) / 128), 256, 0, stream>>>(
      mid_bf, WT2, b2, out, nullptr, nullptr, nullptr, NQ, 256);
}

// Round 13
// 349.710 us; speedup vs baseline: 1.6441x; 1.0361x over previous
//
#include <hip/hip_runtime.h>
#include <hip/hip_bf16.h>
#include <math.h>

#define NQ 40000
#define NV 52500
#define D 256
#define NHEAD 8
#define HD 32
#define GUARD 512   // guard rows around vproj table (clamp-free sampling)

using bf16x8 = __attribute__((ext_vector_type(8))) short;
using f32x4  = __attribute__((ext_vector_type(4))) float;
typedef int v2i32 __attribute__((ext_vector_type(2)));

__device__ __forceinline__ short f2bf(float f) {
  union { __hip_bfloat16 h; short s; } u;
  u.h = __float2bfloat16(f);
  return u.s;
}
__device__ __forceinline__ float bf2f(unsigned short s) {
  return __uint_as_float((unsigned)s << 16);
}
__device__ __forceinline__ unsigned pack2(float lo, float hi) {
  return (unsigned)(unsigned short)f2bf(lo) |
         ((unsigned)(unsigned short)f2bf(hi) << 16);
}
// async global->LDS, 16B per lane, wave-uniform LDS base
__device__ __forceinline__ void gload16(const void* g, void* l) {
  __builtin_amdgcn_global_load_lds(
      (const __attribute__((address_space(1))) unsigned int*)g,
      (__attribute__((address_space(3))) unsigned int*)l, 16, 0, 0);
}

// cross-lane sum helpers: x + x[lane^K]
template<int IMM>
__device__ __forceinline__ float swz_add(float x) {   // K = 4 or 8 (ds pipe)
  return x + __int_as_float(__builtin_amdgcn_ds_swizzle(__float_as_int(x), IMM));
}

// ------------------------------------- all weight prep fused in one kernel
__global__ __launch_bounds__(256) void k_prep(const float* __restrict__ Woff,
                                              const float* __restrict__ Wattn,
                                              const float* __restrict__ Wval,
                                              const float* __restrict__ Wout,
                                              const float* __restrict__ W1,
                                              const float* __restrict__ W2,
                                              const float* __restrict__ boff,
                                              const float* __restrict__ battn,
                                              short* __restrict__ WT288,
                                              short* __restrict__ WTval,
                                              short* __restrict__ WTout,
                                              short* __restrict__ WT1,
                                              short* __restrict__ WT2,
                                              float* __restrict__ bias288) {
  int idx = blockIdx.x * 256 + threadIdx.x;
  if (idx < 49152) {                       // Woff^T  [192][256]
    int n = idx >> 8, k = idx & 255;
    WT288[idx] = f2bf(Woff[k * 192 + n]);
  } else if (idx < 73728) {                // Wattn^T [96][256]
    int li = idx - 49152; int n = li >> 8, k = li & 255;
    WT288[49152 + li] = f2bf(Wattn[k * 96 + n]);
  } else if (idx < 139264) {               // Wval^T [256][256]
    int li = idx - 73728; int n = li >> 8, k = li & 255;
    WTval[li] = f2bf(Wval[k * 256 + n]);
  } else if (idx < 204800) {               // Wout^T [256][256]
    int li = idx - 139264; int n = li >> 8, k = li & 255;
    WTout[li] = f2bf(Wout[k * 256 + n]);
  } else if (idx < 466944) {               // W1^T [1024][256]
    int li = idx - 204800; int n = li >> 8, k = li & 255;
    WT1[li] = f2bf(W1[k * 1024 + n]);
  } else if (idx < 729088) {               // W2^T [256][1024]
    int li = idx - 466944; int n = li >> 10, k = li & 1023;
    WT2[li] = f2bf(W2[k * 256 + n]);
  } else if (idx < 729376) {               // bias288
    int i = idx - 729088;
    bias288[i] = (i < 192) ? boff[i] : battn[i - 192];
  }
}

// ---------------------------------------------- LN1 + qp; iden stored bf16
__global__ __launch_bounds__(256) void k_ln1(const float* __restrict__ qin,
                                             const float* __restrict__ qpos,
                                             const float* __restrict__ g,
                                             const float* __restrict__ b,
                                             short* __restrict__ id_out,
                                             short* __restrict__ qp_out) {
  int wave = threadIdx.x >> 6;
  int lane = threadIdx.x & 63;
  int row  = blockIdx.x * 4 + wave;
  float4 x = ((const float4*)(qin + (size_t)row * D))[lane];
  float s  = x.x + x.y + x.z + x.w;
  float ss = x.x*x.x + x.y*x.y + x.z*x.z + x.w*x.w;
  for (int o = 32; o > 0; o >>= 1) { s += __shfl_down(s, o); ss += __shfl_down(ss, o); }
  s  = __shfl(s, 0);
  ss = __shfl(ss, 0);
  float m   = s * (1.0f / 256.0f);
  float var = ss * (1.0f / 256.0f) - m * m;
  float rs  = rsqrtf(var + 1e-5f);
  float4 gg = ((const float4*)g)[lane];
  float4 bb = ((const float4*)b)[lane];
  float4 qn;
  qn.x = (x.x - m) * rs * gg.x + bb.x;
  qn.y = (x.y - m) * rs * gg.y + bb.y;
  qn.z = (x.z - m) * rs * gg.z + bb.z;
  qn.w = (x.w - m) * rs * gg.w + bb.w;
  short4 io;
  io.x = f2bf(qn.x); io.y = f2bf(qn.y); io.z = f2bf(qn.z); io.w = f2bf(qn.w);
  ((short4*)(id_out + (size_t)row * D))[lane] = io;
  float4 p = ((const float4*)(qpos + (size_t)row * D))[lane];
  short4 o;
  o.x = f2bf(qn.x + p.x); o.y = f2bf(qn.y + p.y);
  o.z = f2bf(qn.z + p.z); o.w = f2bf(qn.w + p.w);
  ((short4*)(qp_out + (size_t)row * D))[lane] = o;
}

// ----------------------------------------------------------- LN2 -> bf16 h
__global__ __launch_bounds__(256) void k_ln2(const float* __restrict__ xin,
                                             const float* __restrict__ g,
                                             const float* __restrict__ b,
                                             short* __restrict__ h_out) {
  int wave = threadIdx.x >> 6;
  int lane = threadIdx.x & 63;
  int row  = blockIdx.x * 4 + wave;
  float4 x = ((const float4*)(xin + (size_t)row * D))[lane];
  float s  = x.x + x.y + x.z + x.w;
  float ss = x.x*x.x + x.y*x.y + x.z*x.z + x.w*x.w;
  for (int o = 32; o > 0; o >>= 1) { s += __shfl_down(s, o); ss += __shfl_down(ss, o); }
  s  = __shfl(s, 0);
  ss = __shfl(ss, 0);
  float m   = s * (1.0f / 256.0f);
  float var = ss * (1.0f / 256.0f) - m * m;
  float rs  = rsqrtf(var + 1e-5f);
  float4 gg = ((const float4*)g)[lane];
  float4 bb = ((const float4*)b)[lane];
  short4 o;
  o.x = f2bf((x.x - m) * rs * gg.x + bb.x);
  o.y = f2bf((x.y - m) * rs * gg.y + bb.y);
  o.z = f2bf((x.z - m) * rs * gg.z + bb.z);
  o.w = f2bf((x.w - m) * rs * gg.w + bb.w);
  ((short4*)(h_out + (size_t)row * D))[lane] = o;
}

// --------------------------------------------------------------- MFMA GEMM
// 128x128 tile, BK=32, triple-buffered LDS, depth-2 counted-vmcnt pipeline.
// LDS-repack epilogue with coalesced dwordx4 I/O. setprio around MFMA.
// EPI: 0 = store f32; 1 = gelu -> bf16; 3 = Cf += v; 4 = store bf16;
//      5 = v + R1(f32) + R2(bf16) -> f32
template<int EPI, int CVTA, int K>
__global__ __launch_bounds__(256) void k_gemm(const void* __restrict__ Ain,
                                              const short* __restrict__ WT,
                                              const float* __restrict__ bias,
                                              float* __restrict__ Cf,
                                              short* __restrict__ Cb,
                                              const float* __restrict__ R1,
                                              const float* __restrict__ R2,
                                              int M, int N) {
  constexpr int NT = K / 32;
  __shared__ short Al[3][4096];
  __shared__ short Bl[3][4096];
  const int tid = threadIdx.x;

  // XCD-chunked bijective block swizzle (T1)
  const int nbx = gridDim.x;
  const int nwg = nbx * gridDim.y;
  int flat = blockIdx.y * nbx + blockIdx.x;
  {
    int xcd = flat & 7, pos = flat >> 3;
    int qq = nwg >> 3, rr = nwg & 7;
    flat = (xcd < rr ? xcd * (qq + 1) : rr * (qq + 1) + (xcd - rr) * qq) + pos;
  }
  const int n0 = (flat % nbx) * 128, m0 = (flat / nbx) * 128;

  const int w = tid >> 6, l = tid & 63;
  const int wm = (w >> 1) * 64, wn = (w & 1) * 64;
  const int lr = l & 15;

  const int c0s = w * 2, c1s = c0s + 1;
  const int sr = l >> 2;
  const int sg = (((l & 3) ^ ((l >> 3) & 3)) << 3);   // swizzled src slot
  const int ar0 = min(m0 + c0s * 16 + sr, M - 1);
  const int ar1 = min(m0 + c1s * 16 + sr, M - 1);
  const int br0 = min(n0 + c0s * 16 + sr, N - 1);
  const int br1 = min(n0 + c1s * 16 + sr, N - 1);
  const short* bP0 = WT + (size_t)br0 * K + sg;
  const short* bP1 = WT + (size_t)br1 * K + sg;
  const short* aP0 = (const short*)Ain + (size_t)ar0 * K + sg;
  const short* aP1 = (const short*)Ain + (size_t)ar1 * K + sg;
  const float* aF0 = (const float*)Ain + (size_t)ar0 * K + sg;
  const float* aF1 = (const float*)Ain + (size_t)ar1 * K + sg;
  short* wD0 = &Al[0][(c0s * 16 + sr) * 32 + ((l & 3) << 3)];
  short* wD1 = &Al[0][(c1s * 16 + sr) * 32 + ((l & 3) << 3)];

  const int fsw = (((l >> 4) ^ ((l >> 1) & 3)) << 3);  // swizzled read slot
  const int aRd = (wm + lr) * 32 + fsw;
  const int bRd = (wn + lr) * 32 + fsw;

  f32x4 acc[4][4];
#pragma unroll
  for (int i = 0; i < 4; ++i)
#pragma unroll
    for (int j = 0; j < 4; ++j) acc[i][j] = (f32x4){0, 0, 0, 0};

  if (CVTA) {
    // ---------------- 2-phase reg-staged cvt path ------------------------
    {
      float4 f00 = *(const float4*)(aF0);
      float4 f01 = *(const float4*)(aF0 + 4);
      float4 f10 = *(const float4*)(aF1);
      float4 f11 = *(const float4*)(aF1 + 4);
      int4 p0, p1;
      p0.x = pack2(f00.x, f00.y); p0.y = pack2(f00.z, f00.w);
      p0.z = pack2(f01.x, f01.y); p0.w = pack2(f01.z, f01.w);
      p1.x = pack2(f10.x, f10.y); p1.y = pack2(f10.z, f10.w);
      p1.z = pack2(f11.x, f11.y); p1.w = pack2(f11.z, f11.w);
      *(int4*)wD0 = p0;
      *(int4*)wD1 = p1;
      gload16(bP0, &Bl[0][c0s * 512]);
      gload16(bP1, &Bl[0][c1s * 512]);
      __syncthreads();
    }
#pragma unroll 2
    for (int t = 0; t < NT - 1; ++t) {
      const int buf = t & 1, nbuf = buf ^ 1;
      const int kn = (t + 1) * 32;
      float4 f00 = *(const float4*)(aF0 + kn);
      float4 f01 = *(const float4*)(aF0 + kn + 4);
      float4 f10 = *(const float4*)(aF1 + kn);
      float4 f11 = *(const float4*)(aF1 + kn + 4);
      gload16(bP0 + kn, &Bl[nbuf][c0s * 512]);
      gload16(bP1 + kn, &Bl[nbuf][c1s * 512]);

      bf16x8 af[4], bfr[4];
#pragma unroll
      for (int i = 0; i < 4; ++i) {
        af[i]  = *(const bf16x8*)&Al[buf][aRd + i * 512];
        bfr[i] = *(const bf16x8*)&Bl[buf][bRd + i * 512];
      }
#pragma unroll
      for (int i = 0; i < 4; ++i)
#pragma unroll
        for (int j = 0; j < 4; ++j)
          acc[i][j] = __builtin_amdgcn_mfma_f32_16x16x32_bf16(af[i], bfr[j], acc[i][j], 0, 0, 0);

      int4 p0, p1;
      p0.x = pack2(f00.x, f00.y); p0.y = pack2(f00.z, f00.w);
      p0.z = pack2(f01.x, f01.y); p0.w = pack2(f01.z, f01.w);
      p1.x = pack2(f10.x, f10.y); p1.y = pack2(f10.z, f10.w);
      p1.z = pack2(f11.x, f11.y); p1.w = pack2(f11.z, f11.w);
      *(int4*)(wD0 + nbuf * 4096) = p0;
      *(int4*)(wD1 + nbuf * 4096) = p1;
      __syncthreads();
    }
    {
      const int buf = (NT - 1) & 1;
      bf16x8 af[4], bfr[4];
#pragma unroll
      for (int i = 0; i < 4; ++i) {
        af[i]  = *(const bf16x8*)&Al[buf][aRd + i * 512];
        bfr[i] = *(const bf16x8*)&Bl[buf][bRd + i * 512];
      }
#pragma unroll
      for (int i = 0; i < 4; ++i)
#pragma unroll
        for (int j = 0; j < 4; ++j)
          acc[i][j] = __builtin_amdgcn_mfma_f32_16x16x32_bf16(af[i], bfr[j], acc[i][j], 0, 0, 0);
    }
  } else {
    // ---------------- depth-2 counted-vmcnt pipeline, 3 buffers ----------
    gload16(aP0, &Al[0][c0s * 512]);
    gload16(aP1, &Al[0][c1s * 512]);
    gload16(bP0, &Bl[0][c0s * 512]);
    gload16(bP1, &Bl[0][c1s * 512]);
    if (NT > 1) {
      gload16(aP0 + 32, &Al[1][c0s * 512]);
      gload16(aP1 + 32, &Al[1][c1s * 512]);
      gload16(bP0 + 32, &Bl[1][c0s * 512]);
      gload16(bP1 + 32, &Bl[1][c1s * 512]);
    }
#pragma unroll
    for (int t = 0; t < NT; ++t) {
      const int buf = t % 3;
      if (t + 1 < NT) asm volatile("s_waitcnt vmcnt(4)" ::: "memory");
      else            asm volatile("s_waitcnt vmcnt(0)" ::: "memory");
      __builtin_amdgcn_s_barrier();
      __builtin_amdgcn_sched_barrier(0);
      if (t + 2 < NT) {
        const int kn = (t + 2) * 32, nb = (t + 2) % 3;
        gload16(aP0 + kn, &Al[nb][c0s * 512]);
        gload16(aP1 + kn, &Al[nb][c1s * 512]);
        gload16(bP0 + kn, &Bl[nb][c0s * 512]);
        gload16(bP1 + kn, &Bl[nb][c1s * 512]);
      }
      bf16x8 af[4], bfr[4];
#pragma unroll
      for (int i = 0; i < 4; ++i) {
        af[i]  = *(const bf16x8*)&Al[buf][aRd + i * 512];
        bfr[i] = *(const bf16x8*)&Bl[buf][bRd + i * 512];
      }
      __builtin_amdgcn_s_setprio(1);
#pragma unroll
      for (int i = 0; i < 4; ++i)
#pragma unroll
        for (int j = 0; j < 4; ++j)
          acc[i][j] = __builtin_amdgcn_mfma_f32_16x16x32_bf16(af[i], bfr[j], acc[i][j], 0, 0, 0);
      __builtin_amdgcn_s_setprio(0);
    }
  }

  // ---------------- epilogue: LDS-repacked coalesced I/O -------------------
  __syncthreads();                        // all K-loop LDS reads complete
  float* scratch = (float*)&Al[0][0];     // 32 x 140 f32 = 17.9 KB
  const unsigned short* R2b = (const unsigned short*)R2;
  const int wrow = (w >> 1) * 16;
  const int rl2 = tid >> 3;               // 0..31 chunk-local row
  const int cc0 = (tid & 7) * 16;         // 0..112 col base
  const bool colok = (n0 + cc0) < N;
  float bsv[16];
#pragma unroll
  for (int c = 0; c < 4; ++c) {
    float4 bv = {0, 0, 0, 0};
    if (colok) bv = *(const float4*)&bias[n0 + cc0 + c * 4];
    bsv[c*4+0] = bv.x; bsv[c*4+1] = bv.y; bsv[c*4+2] = bv.z; bsv[c*4+3] = bv.w;
  }
#pragma unroll
  for (int i = 0; i < 4; ++i) {
#pragma unroll
    for (int j = 0; j < 4; ++j) {
      const int col = wn + j * 16 + (l & 15);
      const int rbase = wrow + ((l >> 4) << 2);
#pragma unroll
      for (int r = 0; r < 4; ++r)
        scratch[(rbase + r) * 140 + col] = acc[i][j][r];
    }
    __syncthreads();
    const int grow = m0 + 16 * i + (rl2 < 16 ? rl2 : 48 + rl2);
    if (colok && grow < M) {
      const size_t base = (size_t)grow * N + n0 + cc0;
      float v16[16];
#pragma unroll
      for (int c = 0; c < 4; ++c) {
        float4 vv = *(const float4*)&scratch[rl2 * 140 + cc0 + c * 4];
        v16[c*4+0] = vv.x + bsv[c*4+0];
        v16[c*4+1] = vv.y + bsv[c*4+1];
        v16[c*4+2] = vv.z + bsv[c*4+2];
        v16[c*4+3] = vv.w + bsv[c*4+3];
      }
      if (EPI == 0) {
#pragma unroll
        for (int c = 0; c < 4; ++c)
          *(float4*)&Cf[base + c * 4] =
              (float4){v16[c*4], v16[c*4+1], v16[c*4+2], v16[c*4+3]};
      } else if (EPI == 1) {
        unsigned pk[8];
#pragma unroll
        for (int c = 0; c < 8; ++c) {
          float a0 = v16[2*c], a1 = v16[2*c+1];
          float u0 = a0 * (2.3021178f + 0.1029445f * a0 * a0);
          float u1 = a1 * (2.3021178f + 0.1029445f * a1 * a1);
          float g0 = a0 - a0 / (1.0f + exp2f(u0));
          float g1 = a1 - a1 / (1.0f + exp2f(u1));
          pk[c] = pack2(g0, g1);
        }
        *(uint4*)&Cb[base] = (uint4){pk[0], pk[1], pk[2], pk[3]};
        *(uint4*)&Cb[base + 8] = (uint4){pk[4], pk[5], pk[6], pk[7]};
      } else if (EPI == 5) {
        uint4 rb0 = *(const uint4*)&R2b[base];
        uint4 rb1 = *(const uint4*)&R2b[base + 8];
        unsigned rw[8] = {rb0.x, rb0.y, rb0.z, rb0.w, rb1.x, rb1.y, rb1.z, rb1.w};
        float r2v[16];
#pragma unroll
        for (int c = 0; c < 8; ++c) {
          r2v[2*c]   = __uint_as_float(rw[c] << 16);
          r2v[2*c+1] = __uint_as_float(rw[c] & 0xffff0000u);
        }
#pragma unroll
        for (int c = 0; c < 4; ++c) {
          float4 r1 = *(const float4*)&R1[base + c * 4];
          *(float4*)&Cf[base + c * 4] =
              (float4){v16[c*4] + r1.x + r2v[c*4], v16[c*4+1] + r1.y + r2v[c*4+1],
                       v16[c*4+2] + r1.z + r2v[c*4+2], v16[c*4+3] + r1.w + r2v[c*4+3]};
        }
      } else if (EPI == 3) {
#pragma unroll
        for (int c = 0; c < 4; ++c) {
          float4 cur = *(const float4*)&Cf[base + c * 4];
          *(float4*)&Cf[base + c * 4] =
              (float4){cur.x + v16[c*4], cur.y + v16[c*4+1],
                       cur.z + v16[c*4+2], cur.w + v16[c*4+3]};
        }
      } else {
        uint4 o0 = (uint4){pack2(v16[0], v16[1]), pack2(v16[2], v16[3]),
                           pack2(v16[4], v16[5]), pack2(v16[6], v16[7])};
        uint4 o1 = (uint4){pack2(v16[8], v16[9]), pack2(v16[10], v16[11]),
                           pack2(v16[12], v16[13]), pack2(v16[14], v16[15])};
        *(uint4*)&Cb[base] = o0;
        *(uint4*)&Cb[base + 8] = o1;
      }
    }
    __syncthreads();
  }
}

// -------- softmax + sampling meta: idxB[qh][16] + wT[qh][tap][16] (bf16)
__global__ __launch_bounds__(256) void k_post(const unsigned short* __restrict__ res,
                                              const float* __restrict__ refp,
                                              int* __restrict__ idxB,
                                              unsigned short* __restrict__ wT) {
  int t = blockIdx.x * 256 + threadIdx.x;
  if (t >= NQ * 8) return;
  int q = t >> 3, h = t & 7;
  const unsigned short* rr = res + (size_t)q * 288;
  const unsigned short* lg = rr + 192 + h * 12;
  float lf[12];
#pragma unroll
  for (int i = 0; i < 12; ++i) lf[i] = bf2f(lg[i]);
  float mx = lf[0];
#pragma unroll
  for (int i = 1; i < 12; ++i) mx = fmaxf(mx, lf[i]);
  float e[12]; float sum = 0.0f;
#pragma unroll
  for (int i = 0; i < 12; ++i) { e[i] = expf(lf[i] - mx); sum += e[i]; }
  float inv = 1.0f / sum;

  const float dims[3] = {200.0f, 100.0f, 50.0f};
  const int   sts[3]  = {0, 40000, 50000};
  int* idq = idxB + (size_t)t * 16;
  unsigned short* wq = wT + (size_t)t * 64;   // [4 taps][16]
#pragma unroll
  for (int l = 0; l < 3; ++l) {
    const int W = (int)dims[l];
    const float fW = dims[l];
    float rx = refp[((size_t)q * 3 + l) * 2 + 0];
    float ry = refp[((size_t)q * 3 + l) * 2 + 1];
    float invd = 1.0f / fW;
#pragma unroll
    for (int p = 0; p < 4; ++p) {
      int j = ((h * 3 + l) * 4 + p) * 2;
      float lx = rx + bf2f(rr[j + 0]) * invd;
      float ly = ry + bf2f(rr[j + 1]) * invd;
      float fx = lx * fW - 0.5f;
      float fy = ly * fW - 0.5f;
      float x0f = floorf(fx), y0f = floorf(fy);
      float tx = fx - x0f, ty = fy - y0f;
      int x0 = (int)x0f, y0 = (int)y0f;
      bool vx0 = (unsigned)x0       < (unsigned)W;
      bool vx1 = (unsigned)(x0 + 1) < (unsigned)W;
      bool vy0 = (unsigned)y0       < (unsigned)W;
      bool vy1 = (unsigned)(y0 + 1) < (unsigned)W;
      float a = e[l * 4 + p] * inv;
      float w00 = (vx0 && vy0) ? a * (1.0f - tx) * (1.0f - ty) : 0.0f;
      float w01 = (vx1 && vy0) ? a * tx * (1.0f - ty) : 0.0f;
      float w10 = (vx0 && vy1) ? a * (1.0f - tx) * ty : 0.0f;
      float w11 = (vx1 && vy1) ? a * tx * ty : 0.0f;
      int pt = l * 4 + p;
      idq[pt] = sts[l] + y0 * W + x0;
      wq[0 * 16 + pt] = (unsigned short)f2bf(w00);
      wq[1 * 16 + pt] = (unsigned short)f2bf(w01);
      wq[2 * 16 + pt] = (unsigned short)f2bf(w10);
      wq[3 * 16 + pt] = (unsigned short)f2bf(w11);
    }
  }
}

// ----------------------------------------------------------- deform sampling
// One wave = 4 (q,h). lane = qh-slot(2b) | tap(2b) | cq(2b).
// Meta hoisted out of the loop: myidx (1 coalesced load) + 12 tap-weights
// in registers (2 loads). Loop = 12 x {ds_bpermute + gather}.
__global__ __launch_bounds__(256) void k_sample(const short* __restrict__ vprojG,
                                                const int* __restrict__ idxB,
                                                const unsigned short* __restrict__ wT,
                                                short* __restrict__ smp) {
  const int lane = threadIdx.x & 63;
  const int slot = lane >> 4;
  const int qh   = blockIdx.x * 16 + (threadIdx.x >> 6) * 4 + slot;
  const int tap  = (lane >> 2) & 3;  // dy,dx
  const int cq   = lane & 3;         // channel oct (8 ch)
  const int h = qh & 7;
  const int dy = tap >> 1, dx = tap & 1;
  const short* vb = vprojG + (size_t)GUARD * D + h * HD + cq * 8;

  // meta preload
  const int myidx = idxB[(size_t)qh * 16 + (lane & 15)];
  const unsigned short* wp = wT + ((size_t)qh * 4 + tap) * 16;
  uint4 w8 = *(const uint4*)wp;            // weights 0..7
  uint2 w4 = *(const uint2*)(wp + 8);      // weights 8..11
  const unsigned wd[6] = {w8.x, w8.y, w8.z, w8.w, w4.x, w4.y};

  float acc[8];
#pragma unroll
  for (int j = 0; j < 8; ++j) acc[j] = 0.0f;

  const int Dim[3] = {200, 100, 50};
  const int slotbase = slot << 4;
#pragma unroll
  for (int it = 0; it < 12; ++it) {
    const int W = Dim[it >> 2];
    int idx0 = __builtin_amdgcn_ds_bpermute((slotbase + it) << 2, myidx);
    int idx = idx0 + dy * W + dx;
    unsigned wraw = wd[it >> 1];
    float wgt = __uint_as_float((it & 1) ? (wraw & 0xffff0000u) : (wraw << 16));
    uint4 v = *(const uint4*)(vb + (ptrdiff_t)idx * D);
    acc[0] = fmaf(wgt, __uint_as_float(v.x << 16),         acc[0]);
    acc[1] = fmaf(wgt, __uint_as_float(v.x & 0xffff0000u), acc[1]);
    acc[2] = fmaf(wgt, __uint_as_float(v.y << 16),         acc[2]);
    acc[3] = fmaf(wgt, __uint_as_float(v.y & 0xffff0000u), acc[3]);
    acc[4] = fmaf(wgt, __uint_as_float(v.z << 16),         acc[4]);
    acc[5] = fmaf(wgt, __uint_as_float(v.z & 0xffff0000u), acc[5]);
    acc[6] = fmaf(wgt, __uint_as_float(v.w << 16),         acc[6]);
    acc[7] = fmaf(wgt, __uint_as_float(v.w & 0xffff0000u), acc[7]);
  }

  // tap reduce only (lane bits 2,3)
#pragma unroll
  for (int j = 0; j < 8; ++j) {
    float a = swz_add<0x101F>(acc[j]);   // ^4
    acc[j] = swz_add<0x201F>(a);         // ^8
  }

  if (tap == 0) {
    uint4 o;
    o.x = pack2(acc[0], acc[1]);
    o.y = pack2(acc[2], acc[3]);
    o.z = pack2(acc[4], acc[5]);
    o.w = pack2(acc[6], acc[7]);
    *(uint4*)(smp + (size_t)qh * HD + cq * 8) = o;
  }
}

// ---------------------------------------------------------------------------
extern "C" void kernel_launch(void* const* d_in, const int* in_sizes, int n_in,
                              void* d_out, int out_size, void* d_ws, size_t ws_size,
                              hipStream_t stream) {
  const float* query  = (const float*)d_in[0];
  const float* value  = (const float*)d_in[1];
  const float* qpos   = (const float*)d_in[2];
  const float* refp   = (const float*)d_in[3];
  const float* n1g = (const float*)d_in[6];
  const float* n1b = (const float*)d_in[7];
  const float* Woff = (const float*)d_in[8];
  const float* boff = (const float*)d_in[9];
  const float* Wattn = (const float*)d_in[10];
  const float* battn = (const float*)d_in[11];
  const float* Wval = (const float*)d_in[12];
  const float* bval = (const float*)d_in[13];
  const float* Wout = (const float*)d_in[14];
  const float* bout = (const float*)d_in[15];
  const float* n2g = (const float*)d_in[16];
  const float* n2b = (const float*)d_in[17];
  const float* W1 = (const float*)d_in[18];
  const float* b1 = (const float*)d_in[19];
  const float* W2 = (const float*)d_in[20];
  const float* b2 = (const float*)d_in[21];

  float* out = (float*)d_out;
  char* Wb = (char*)d_ws;

  // workspace layout (time-overlaid; ~152 MB total)
  short* qp_bf   = (short*)Wb;                    // [0,20.48M)  ln1 -> gemm288
  short* iden_bf = (short*)(Wb + 20480000);       // [20.48,40.96M) ln1 -> outproj
  int*   idxB    = (int*)(Wb + 40960000);         // [40.96,61.44M) post -> sample
  unsigned short* wT = (unsigned short*)(Wb + 61440000); // [61.44,102.4M)
  short* res_bf  = (short*)(Wb + 102400000);      // 23.04MB gemm288 -> post
  short* vprjG   = (short*)(Wb + 102400000);      // guard+26.88MB+guard -> sample
  short* vprj_bf = (short*)(Wb + 102400000 + GUARD * D * 2);
  short* h_bf    = (short*)(Wb + 102400000);      // 20.48MB ln2 -> ffn1
  short* smp_bf  = (short*)(Wb + 130000000);      // 20.48MB sample -> outproj
  short* mid_bf  = (short*)Wb;                    // [0,81.92M) ffn1 -> ffn2
  char*  Wbase   = Wb + 150600000;
  short* WT288   = (short*)(Wbase);
  short* WTval   = (short*)(Wbase + 147456);
  short* WTout   = (short*)(Wbase + 278528);
  short* WT1     = (short*)(Wbase + 409600);
  short* WT2     = (short*)(Wbase + 933888);
  float* bias288 = (float*)(Wbase + 1458176);

  // weight prep (single fused kernel)
  k_prep<<<(729376 + 255) / 256, 256, 0, stream>>>(
      Woff, Wattn, Wval, Wout, W1, W2, boff, battn,
      WT288, WTval, WTout, WT1, WT2, bias288);

  // LN1 -> iden(bf16), qp(bf16)
  k_ln1<<<NQ / 4, 256, 0, stream>>>(query, qpos, n1g, n1b, iden_bf, qp_bf);

  // offsets+attn logits GEMM (N=288) -> bf16 res
  k_gemm<4,0,256><<<dim3(3, (NQ + 127) / 128), 256, 0, stream>>>(
      qp_bf, WT288, bias288, nullptr, res_bf, nullptr, nullptr, NQ, 288);
  // softmax + sampling meta
  k_post<<<(NQ * 8 + 255) / 256, 256, 0, stream>>>(
      (const unsigned short*)res_bf, refp, idxB, wT);

  // value proj (fused f32->bf16 A staging) -> bf16 (guard-padded table)
  k_gemm<4,1,256><<<dim3(2, (NV + 127) / 128), 256, 0, stream>>>(
      value, WTval, bval, nullptr, vprj_bf, nullptr, nullptr, NV, 256);

  // deformable sampling -> smp(bf16); 4 qh per wave, 16 per block
  k_sample<<<NQ * NHEAD / 16, 256, 0, stream>>>(vprjG, idxB, wT, smp_bf);

  // out proj + residuals (query f32 + iden bf16) -> x (d_out)
  k_gemm<5,0,256><<<dim3(2, (NQ + 127) / 128), 256, 0, stream>>>(
      smp_bf, WTout, bout, out, nullptr, query, (const float*)iden_bf, NQ, 256);

  // LN2 -> h(bf16)
  k_ln2<<<NQ / 4, 256, 0, stream>>>(out, n2g, n2b, h_bf);

  // FFN1: gelu(h@W1+b1) -> mid(bf16)
  k_gemm<1,0,256><<<dim3(8, (NQ + 127) / 128), 256, 0, stream>>>(
      h_bf, WT1, b1, nullptr, mid_bf, nullptr, nullptr, NQ, 1024);

  // FFN2: x += mid@W2+b2 (in place on d_out)
  k_gemm<3,0,1024><<<dim3(2, (NQ + 127) / 128), 256, 0, stream>>>(
      mid_bf, WT2, b2, out, nullptr, nullptr, nullptr, NQ, 256);
}

// Round 14
// 333.245 us; speedup vs baseline: 1.7253x; 1.0494x over previous
//
#include <hip/hip_runtime.h>
#include <hip/hip_bf16.h>
#include <math.h>

#define NQ 40000
#define NV 52500
#define D 256
#define NHEAD 8
#define HD 32
#define GUARD 512   // guard rows around vproj table (clamp-free sampling)

using bf16x8 = __attribute__((ext_vector_type(8))) short;
using f32x4  = __attribute__((ext_vector_type(4))) float;
typedef int v2i32 __attribute__((ext_vector_type(2)));

__device__ __forceinline__ short f2bf(float f) {
  union { __hip_bfloat16 h; short s; } u;
  u.h = __float2bfloat16(f);
  return u.s;
}
__device__ __forceinline__ float bf2f(unsigned short s) {
  return __uint_as_float((unsigned)s << 16);
}
__device__ __forceinline__ unsigned pack2(float lo, float hi) {
  return (unsigned)(unsigned short)f2bf(lo) |
         ((unsigned)(unsigned short)f2bf(hi) << 16);
}
// async global->LDS, 16B per lane, wave-uniform LDS base
__device__ __forceinline__ void gload16(const void* g, void* l) {
  __builtin_amdgcn_global_load_lds(
      (const __attribute__((address_space(1))) unsigned int*)g,
      (__attribute__((address_space(3))) unsigned int*)l, 16, 0, 0);
}

// cross-lane sum helpers: x + x[lane^K]
template<int IMM>
__device__ __forceinline__ float swz_add(float x) {   // K = 4 or 8 (ds pipe)
  return x + __int_as_float(__builtin_amdgcn_ds_swizzle(__float_as_int(x), IMM));
}

// ------------------------------------- all weight prep fused in one kernel
__global__ __launch_bounds__(256) void k_prep(const float* __restrict__ Woff,
                                              const float* __restrict__ Wattn,
                                              const float* __restrict__ Wval,
                                              const float* __restrict__ Wout,
                                              const float* __restrict__ W1,
                                              const float* __restrict__ W2,
                                              const float* __restrict__ boff,
                                              const float* __restrict__ battn,
                                              short* __restrict__ WT288,
                                              short* __restrict__ WTval,
                                              short* __restrict__ WTout,
                                              short* __restrict__ WT1,
                                              short* __restrict__ WT2,
                                              float* __restrict__ bias288) {
  int idx = blockIdx.x * 256 + threadIdx.x;
  if (idx < 49152) {                       // Woff^T  [192][256]
    int n = idx >> 8, k = idx & 255;
    WT288[idx] = f2bf(Woff[k * 192 + n]);
  } else if (idx < 73728) {                // Wattn^T [96][256]
    int li = idx - 49152; int n = li >> 8, k = li & 255;
    WT288[49152 + li] = f2bf(Wattn[k * 96 + n]);
  } else if (idx < 139264) {               // Wval^T [256][256]
    int li = idx - 73728; int n = li >> 8, k = li & 255;
    WTval[li] = f2bf(Wval[k * 256 + n]);
  } else if (idx < 204800) {               // Wout^T [256][256]
    int li = idx - 139264; int n = li >> 8, k = li & 255;
    WTout[li] = f2bf(Wout[k * 256 + n]);
  } else if (idx < 466944) {               // W1^T [1024][256]
    int li = idx - 204800; int n = li >> 8, k = li & 255;
    WT1[li] = f2bf(W1[k * 1024 + n]);
  } else if (idx < 729088) {               // W2^T [256][1024]
    int li = idx - 466944; int n = li >> 10, k = li & 1023;
    WT2[li] = f2bf(W2[k * 256 + n]);
  } else if (idx < 729376) {               // bias288
    int i = idx - 729088;
    bias288[i] = (i < 192) ? boff[i] : battn[i - 192];
  }
}

// ---------------------------------------------- LN1 + qp; iden stored bf16
__global__ __launch_bounds__(256) void k_ln1(const float* __restrict__ qin,
                                             const float* __restrict__ qpos,
                                             const float* __restrict__ g,
                                             const float* __restrict__ b,
                                             short* __restrict__ id_out,
                                             short* __restrict__ qp_out) {
  int wave = threadIdx.x >> 6;
  int lane = threadIdx.x & 63;
  int row  = blockIdx.x * 4 + wave;
  float4 x = ((const float4*)(qin + (size_t)row * D))[lane];
  float s  = x.x + x.y + x.z + x.w;
  float ss = x.x*x.x + x.y*x.y + x.z*x.z + x.w*x.w;
  for (int o = 32; o > 0; o >>= 1) { s += __shfl_down(s, o); ss += __shfl_down(ss, o); }
  s  = __shfl(s, 0);
  ss = __shfl(ss, 0);
  float m   = s * (1.0f / 256.0f);
  float var = ss * (1.0f / 256.0f) - m * m;
  float rs  = rsqrtf(var + 1e-5f);
  float4 gg = ((const float4*)g)[lane];
  float4 bb = ((const float4*)b)[lane];
  float4 qn;
  qn.x = (x.x - m) * rs * gg.x + bb.x;
  qn.y = (x.y - m) * rs * gg.y + bb.y;
  qn.z = (x.z - m) * rs * gg.z + bb.z;
  qn.w = (x.w - m) * rs * gg.w + bb.w;
  short4 io;
  io.x = f2bf(qn.x); io.y = f2bf(qn.y); io.z = f2bf(qn.z); io.w = f2bf(qn.w);
  ((short4*)(id_out + (size_t)row * D))[lane] = io;
  float4 p = ((const float4*)(qpos + (size_t)row * D))[lane];
  short4 o;
  o.x = f2bf(qn.x + p.x); o.y = f2bf(qn.y + p.y);
  o.z = f2bf(qn.z + p.z); o.w = f2bf(qn.w + p.w);
  ((short4*)(qp_out + (size_t)row * D))[lane] = o;
}

// ----------------------------------------------------------- LN2 -> bf16 h
__global__ __launch_bounds__(256) void k_ln2(const float* __restrict__ xin,
                                             const float* __restrict__ g,
                                             const float* __restrict__ b,
                                             short* __restrict__ h_out) {
  int wave = threadIdx.x >> 6;
  int lane = threadIdx.x & 63;
  int row  = blockIdx.x * 4 + wave;
  float4 x = ((const float4*)(xin + (size_t)row * D))[lane];
  float s  = x.x + x.y + x.z + x.w;
  float ss = x.x*x.x + x.y*x.y + x.z*x.z + x.w*x.w;
  for (int o = 32; o > 0; o >>= 1) { s += __shfl_down(s, o); ss += __shfl_down(ss, o); }
  s  = __shfl(s, 0);
  ss = __shfl(ss, 0);
  float m   = s * (1.0f / 256.0f);
  float var = ss * (1.0f / 256.0f) - m * m;
  float rs  = rsqrtf(var + 1e-5f);
  float4 gg = ((const float4*)g)[lane];
  float4 bb = ((const float4*)b)[lane];
  short4 o;
  o.x = f2bf((x.x - m) * rs * gg.x + bb.x);
  o.y = f2bf((x.y - m) * rs * gg.y + bb.y);
  o.z = f2bf((x.z - m) * rs * gg.z + bb.z);
  o.w = f2bf((x.w - m) * rs * gg.w + bb.w);
  ((short4*)(h_out + (size_t)row * D))[lane] = o;
}

// --------------------------------------------------------------- MFMA GEMM
// 128x128 tile, BK=32, triple-buffered LDS, depth-2 counted-vmcnt pipeline.
// Epilogue: WAVE-PRIVATE LDS repack (barrier-free; one barrier total).
// EPI: 0 = store f32; 1 = gelu -> bf16; 3 = Cf += v; 4 = store bf16;
//      5 = v + R1(f32) + R2(bf16) -> f32
template<int EPI, int CVTA, int K>
__global__ __launch_bounds__(256) void k_gemm(const void* __restrict__ Ain,
                                              const short* __restrict__ WT,
                                              const float* __restrict__ bias,
                                              float* __restrict__ Cf,
                                              short* __restrict__ Cb,
                                              const float* __restrict__ R1,
                                              const float* __restrict__ R2,
                                              int M, int N) {
  constexpr int NT = K / 32;
  __shared__ short Al[3][4096];
  __shared__ short Bl[3][4096];
  const int tid = threadIdx.x;

  // XCD-chunked bijective block swizzle (T1)
  const int nbx = gridDim.x;
  const int nwg = nbx * gridDim.y;
  int flat = blockIdx.y * nbx + blockIdx.x;
  {
    int xcd = flat & 7, pos = flat >> 3;
    int qq = nwg >> 3, rr = nwg & 7;
    flat = (xcd < rr ? xcd * (qq + 1) : rr * (qq + 1) + (xcd - rr) * qq) + pos;
  }
  const int n0 = (flat % nbx) * 128, m0 = (flat / nbx) * 128;

  const int w = tid >> 6, l = tid & 63;
  const int wm = (w >> 1) * 64, wn = (w & 1) * 64;
  const int lr = l & 15;

  const int c0s = w * 2, c1s = c0s + 1;
  const int sr = l >> 2;
  const int sg = (((l & 3) ^ ((l >> 3) & 3)) << 3);   // swizzled src slot
  const int ar0 = min(m0 + c0s * 16 + sr, M - 1);
  const int ar1 = min(m0 + c1s * 16 + sr, M - 1);
  const int br0 = min(n0 + c0s * 16 + sr, N - 1);
  const int br1 = min(n0 + c1s * 16 + sr, N - 1);
  const short* bP0 = WT + (size_t)br0 * K + sg;
  const short* bP1 = WT + (size_t)br1 * K + sg;
  const short* aP0 = (const short*)Ain + (size_t)ar0 * K + sg;
  const short* aP1 = (const short*)Ain + (size_t)ar1 * K + sg;
  const float* aF0 = (const float*)Ain + (size_t)ar0 * K + sg;
  const float* aF1 = (const float*)Ain + (size_t)ar1 * K + sg;
  short* wD0 = &Al[0][(c0s * 16 + sr) * 32 + ((l & 3) << 3)];
  short* wD1 = &Al[0][(c1s * 16 + sr) * 32 + ((l & 3) << 3)];

  const int fsw = (((l >> 4) ^ ((l >> 1) & 3)) << 3);  // swizzled read slot
  const int aRd = (wm + lr) * 32 + fsw;
  const int bRd = (wn + lr) * 32 + fsw;

  f32x4 acc[4][4];
#pragma unroll
  for (int i = 0; i < 4; ++i)
#pragma unroll
    for (int j = 0; j < 4; ++j) acc[i][j] = (f32x4){0, 0, 0, 0};

  if (CVTA) {
    // ---------------- 2-phase reg-staged cvt path ------------------------
    {
      float4 f00 = *(const float4*)(aF0);
      float4 f01 = *(const float4*)(aF0 + 4);
      float4 f10 = *(const float4*)(aF1);
      float4 f11 = *(const float4*)(aF1 + 4);
      int4 p0, p1;
      p0.x = pack2(f00.x, f00.y); p0.y = pack2(f00.z, f00.w);
      p0.z = pack2(f01.x, f01.y); p0.w = pack2(f01.z, f01.w);
      p1.x = pack2(f10.x, f10.y); p1.y = pack2(f10.z, f10.w);
      p1.z = pack2(f11.x, f11.y); p1.w = pack2(f11.z, f11.w);
      *(int4*)wD0 = p0;
      *(int4*)wD1 = p1;
      gload16(bP0, &Bl[0][c0s * 512]);
      gload16(bP1, &Bl[0][c1s * 512]);
      __syncthreads();
    }
#pragma unroll 2
    for (int t = 0; t < NT - 1; ++t) {
      const int buf = t & 1, nbuf = buf ^ 1;
      const int kn = (t + 1) * 32;
      float4 f00 = *(const float4*)(aF0 + kn);
      float4 f01 = *(const float4*)(aF0 + kn + 4);
      float4 f10 = *(const float4*)(aF1 + kn);
      float4 f11 = *(const float4*)(aF1 + kn + 4);
      gload16(bP0 + kn, &Bl[nbuf][c0s * 512]);
      gload16(bP1 + kn, &Bl[nbuf][c1s * 512]);

      bf16x8 af[4], bfr[4];
#pragma unroll
      for (int i = 0; i < 4; ++i) {
        af[i]  = *(const bf16x8*)&Al[buf][aRd + i * 512];
        bfr[i] = *(const bf16x8*)&Bl[buf][bRd + i * 512];
      }
#pragma unroll
      for (int i = 0; i < 4; ++i)
#pragma unroll
        for (int j = 0; j < 4; ++j)
          acc[i][j] = __builtin_amdgcn_mfma_f32_16x16x32_bf16(af[i], bfr[j], acc[i][j], 0, 0, 0);

      int4 p0, p1;
      p0.x = pack2(f00.x, f00.y); p0.y = pack2(f00.z, f00.w);
      p0.z = pack2(f01.x, f01.y); p0.w = pack2(f01.z, f01.w);
      p1.x = pack2(f10.x, f10.y); p1.y = pack2(f10.z, f10.w);
      p1.z = pack2(f11.x, f11.y); p1.w = pack2(f11.z, f11.w);
      *(int4*)(wD0 + nbuf * 4096) = p0;
      *(int4*)(wD1 + nbuf * 4096) = p1;
      __syncthreads();
    }
    {
      const int buf = (NT - 1) & 1;
      bf16x8 af[4], bfr[4];
#pragma unroll
      for (int i = 0; i < 4; ++i) {
        af[i]  = *(const bf16x8*)&Al[buf][aRd + i * 512];
        bfr[i] = *(const bf16x8*)&Bl[buf][bRd + i * 512];
      }
#pragma unroll
      for (int i = 0; i < 4; ++i)
#pragma unroll
        for (int j = 0; j < 4; ++j)
          acc[i][j] = __builtin_amdgcn_mfma_f32_16x16x32_bf16(af[i], bfr[j], acc[i][j], 0, 0, 0);
    }
  } else {
    // ---------------- depth-2 counted-vmcnt pipeline, 3 buffers ----------
    gload16(aP0, &Al[0][c0s * 512]);
    gload16(aP1, &Al[0][c1s * 512]);
    gload16(bP0, &Bl[0][c0s * 512]);
    gload16(bP1, &Bl[0][c1s * 512]);
    if (NT > 1) {
      gload16(aP0 + 32, &Al[1][c0s * 512]);
      gload16(aP1 + 32, &Al[1][c1s * 512]);
      gload16(bP0 + 32, &Bl[1][c0s * 512]);
      gload16(bP1 + 32, &Bl[1][c1s * 512]);
    }
#pragma unroll
    for (int t = 0; t < NT; ++t) {
      const int buf = t % 3;
      if (t + 1 < NT) asm volatile("s_waitcnt vmcnt(4)" ::: "memory");
      else            asm volatile("s_waitcnt vmcnt(0)" ::: "memory");
      __builtin_amdgcn_s_barrier();
      __builtin_amdgcn_sched_barrier(0);
      if (t + 2 < NT) {
        const int kn = (t + 2) * 32, nb = (t + 2) % 3;
        gload16(aP0 + kn, &Al[nb][c0s * 512]);
        gload16(aP1 + kn, &Al[nb][c1s * 512]);
        gload16(bP0 + kn, &Bl[nb][c0s * 512]);
        gload16(bP1 + kn, &Bl[nb][c1s * 512]);
      }
      bf16x8 af[4], bfr[4];
#pragma unroll
      for (int i = 0; i < 4; ++i) {
        af[i]  = *(const bf16x8*)&Al[buf][aRd + i * 512];
        bfr[i] = *(const bf16x8*)&Bl[buf][bRd + i * 512];
      }
      __builtin_amdgcn_s_setprio(1);
#pragma unroll
      for (int i = 0; i < 4; ++i)
#pragma unroll
        for (int j = 0; j < 4; ++j)
          acc[i][j] = __builtin_amdgcn_mfma_f32_16x16x32_bf16(af[i], bfr[j], acc[i][j], 0, 0, 0);
      __builtin_amdgcn_s_setprio(0);
    }
  }

  // ------- epilogue: wave-private LDS repack, barrier-free (1 barrier) -----
  __syncthreads();                        // all waves' K-loop LDS reads done
  float* wsc = (float*)&Al[0][0] + w * 1088;   // per-wave [16][68] f32
  const unsigned short* R2b = (const unsigned short*)R2;
  const int rr2 = l >> 2;                 // 0..15 chunk-local row
  const int cp4 = (l & 3) << 2;           // col base within 16-col group
  float bsv[16];
#pragma unroll
  for (int p = 0; p < 4; ++p) {
    int col = n0 + wn + p * 16 + cp4;
    float4 bv = {0, 0, 0, 0};
    if (col < N) bv = *(const float4*)&bias[col];
    bsv[p*4+0] = bv.x; bsv[p*4+1] = bv.y; bsv[p*4+2] = bv.z; bsv[p*4+3] = bv.w;
  }
  const int ec2 = l & 15, er2 = (l >> 4) << 2;
#pragma unroll
  for (int i = 0; i < 4; ++i) {
    // scatter this wave's 16x64 chunk into its private region
#pragma unroll
    for (int j = 0; j < 4; ++j)
#pragma unroll
      for (int r = 0; r < 4; ++r)
        wsc[(er2 + r) * 68 + j * 16 + ec2] = acc[i][j][r];
    const int grow = m0 + wm + i * 16 + rr2;
    if (grow < M) {
#pragma unroll
      for (int p = 0; p < 4; ++p) {
        int col = n0 + wn + p * 16 + cp4;
        if (col >= N) continue;
        float4 vv = *(const float4*)&wsc[rr2 * 68 + p * 16 + cp4];
        float v0 = vv.x + bsv[p*4+0];
        float v1 = vv.y + bsv[p*4+1];
        float v2 = vv.z + bsv[p*4+2];
        float v3 = vv.w + bsv[p*4+3];
        size_t base = (size_t)grow * N + col;
        if (EPI == 0) {
          *(float4*)&Cf[base] = (float4){v0, v1, v2, v3};
        } else if (EPI == 1) {
          float u0 = v0 * (2.3021178f + 0.1029445f * v0 * v0);
          float u1 = v1 * (2.3021178f + 0.1029445f * v1 * v1);
          float u2 = v2 * (2.3021178f + 0.1029445f * v2 * v2);
          float u3 = v3 * (2.3021178f + 0.1029445f * v3 * v3);
          float g0 = v0 - v0 / (1.0f + exp2f(u0));
          float g1 = v1 - v1 / (1.0f + exp2f(u1));
          float g2 = v2 - v2 / (1.0f + exp2f(u2));
          float g3 = v3 - v3 / (1.0f + exp2f(u3));
          *(uint2*)&Cb[base] = (uint2){pack2(g0, g1), pack2(g2, g3)};
        } else if (EPI == 5) {
          float4 r1 = *(const float4*)&R1[base];
          uint2 rb = *(const uint2*)&R2b[base];
          *(float4*)&Cf[base] = (float4){
              v0 + r1.x + __uint_as_float(rb.x << 16),
              v1 + r1.y + __uint_as_float(rb.x & 0xffff0000u),
              v2 + r1.z + __uint_as_float(rb.y << 16),
              v3 + r1.w + __uint_as_float(rb.y & 0xffff0000u)};
        } else if (EPI == 3) {
          float4 cur = *(const float4*)&Cf[base];
          *(float4*)&Cf[base] =
              (float4){cur.x + v0, cur.y + v1, cur.z + v2, cur.w + v3};
        } else {
          *(uint2*)&Cb[base] = (uint2){pack2(v0, v1), pack2(v2, v3)};
        }
      }
    }
  }
}

// -------- softmax + sampling meta: idxB[qh][16] + wT[qh][tap][16] (bf16)
__global__ __launch_bounds__(256) void k_post(const unsigned short* __restrict__ res,
                                              const float* __restrict__ refp,
                                              int* __restrict__ idxB,
                                              unsigned short* __restrict__ wT) {
  int t = blockIdx.x * 256 + threadIdx.x;
  if (t >= NQ * 8) return;
  int q = t >> 3, h = t & 7;
  const unsigned short* rr = res + (size_t)q * 288;
  const unsigned short* lg = rr + 192 + h * 12;
  float lf[12];
#pragma unroll
  for (int i = 0; i < 12; ++i) lf[i] = bf2f(lg[i]);
  float mx = lf[0];
#pragma unroll
  for (int i = 1; i < 12; ++i) mx = fmaxf(mx, lf[i]);
  float e[12]; float sum = 0.0f;
#pragma unroll
  for (int i = 0; i < 12; ++i) { e[i] = expf(lf[i] - mx); sum += e[i]; }
  float inv = 1.0f / sum;

  const float dims[3] = {200.0f, 100.0f, 50.0f};
  const int   sts[3]  = {0, 40000, 50000};
  int* idq = idxB + (size_t)t * 16;
  unsigned short* wq = wT + (size_t)t * 64;   // [4 taps][16]
#pragma unroll
  for (int l = 0; l < 3; ++l) {
    const int W = (int)dims[l];
    const float fW = dims[l];
    float rx = refp[((size_t)q * 3 + l) * 2 + 0];
    float ry = refp[((size_t)q * 3 + l) * 2 + 1];
    float invd = 1.0f / fW;
#pragma unroll
    for (int p = 0; p < 4; ++p) {
      int j = ((h * 3 + l) * 4 + p) * 2;
      float lx = rx + bf2f(rr[j + 0]) * invd;
      float ly = ry + bf2f(rr[j + 1]) * invd;
      float fx = lx * fW - 0.5f;
      float fy = ly * fW - 0.5f;
      float x0f = floorf(fx), y0f = floorf(fy);
      float tx = fx - x0f, ty = fy - y0f;
      int x0 = (int)x0f, y0 = (int)y0f;
      bool vx0 = (unsigned)x0       < (unsigned)W;
      bool vx1 = (unsigned)(x0 + 1) < (unsigned)W;
      bool vy0 = (unsigned)y0       < (unsigned)W;
      bool vy1 = (unsigned)(y0 + 1) < (unsigned)W;
      float a = e[l * 4 + p] * inv;
      float w00 = (vx0 && vy0) ? a * (1.0f - tx) * (1.0f - ty) : 0.0f;
      float w01 = (vx1 && vy0) ? a * tx * (1.0f - ty) : 0.0f;
      float w10 = (vx0 && vy1) ? a * (1.0f - tx) * ty : 0.0f;
      float w11 = (vx1 && vy1) ? a * tx * ty : 0.0f;
      int pt = l * 4 + p;
      idq[pt] = sts[l] + y0 * W + x0;
      wq[0 * 16 + pt] = (unsigned short)f2bf(w00);
      wq[1 * 16 + pt] = (unsigned short)f2bf(w01);
      wq[2 * 16 + pt] = (unsigned short)f2bf(w10);
      wq[3 * 16 + pt] = (unsigned short)f2bf(w11);
    }
  }
}

// ----------------------------------------------------------- deform sampling
// One wave = 4 (q,h). lane = qh-slot(2b) | tap(2b) | cq(2b).
// Meta hoisted out of the loop: myidx (1 coalesced load) + 12 tap-weights
// in registers (2 loads). Loop = 12 x {ds_bpermute + gather}.
__global__ __launch_bounds__(256) void k_sample(const short* __restrict__ vprojG,
                                                const int* __restrict__ idxB,
                                                const unsigned short* __restrict__ wT,
                                                short* __restrict__ smp) {
  const int lane = threadIdx.x & 63;
  const int slot = lane >> 4;
  const int qh   = blockIdx.x * 16 + (threadIdx.x >> 6) * 4 + slot;
  const int tap  = (lane >> 2) & 3;  // dy,dx
  const int cq   = lane & 3;         // channel oct (8 ch)
  const int h = qh & 7;
  const int dy = tap >> 1, dx = tap & 1;
  const short* vb = vprojG + (size_t)GUARD * D + h * HD + cq * 8;

  // meta preload
  const int myidx = idxB[(size_t)qh * 16 + (lane & 15)];
  const unsigned short* wp = wT + ((size_t)qh * 4 + tap) * 16;
  uint4 w8 = *(const uint4*)wp;            // weights 0..7
  uint2 w4 = *(const uint2*)(wp + 8);      // weights 8..11
  const unsigned wd[6] = {w8.x, w8.y, w8.z, w8.w, w4.x, w4.y};

  float acc[8];
#pragma unroll
  for (int j = 0; j < 8; ++j) acc[j] = 0.0f;

  const int Dim[3] = {200, 100, 50};
  const int slotbase = slot << 4;
#pragma unroll
  for (int it = 0; it < 12; ++it) {
    const int W = Dim[it >> 2];
    int idx0 = __builtin_amdgcn_ds_bpermute((slotbase + it) << 2, myidx);
    int idx = idx0 + dy * W + dx;
    unsigned wraw = wd[it >> 1];
    float wgt = __uint_as_float((it & 1) ? (wraw & 0xffff0000u) : (wraw << 16));
    uint4 v = *(const uint4*)(vb + (ptrdiff_t)idx * D);
    acc[0] = fmaf(wgt, __uint_as_float(v.x << 16),         acc[0]);
    acc[1] = fmaf(wgt, __uint_as_float(v.x & 0xffff0000u), acc[1]);
    acc[2] = fmaf(wgt, __uint_as_float(v.y << 16),         acc[2]);
    acc[3] = fmaf(wgt, __uint_as_float(v.y & 0xffff0000u), acc[3]);
    acc[4] = fmaf(wgt, __uint_as_float(v.z << 16),         acc[4]);
    acc[5] = fmaf(wgt, __uint_as_float(v.z & 0xffff0000u), acc[5]);
    acc[6] = fmaf(wgt, __uint_as_float(v.w << 16),         acc[6]);
    acc[7] = fmaf(wgt, __uint_as_float(v.w & 0xffff0000u), acc[7]);
  }

  // tap reduce only (lane bits 2,3)
#pragma unroll
  for (int j = 0; j < 8; ++j) {
    float a = swz_add<0x101F>(acc[j]);   // ^4
    acc[j] = swz_add<0x201F>(a);         // ^8
  }

  if (tap == 0) {
    uint4 o;
    o.x = pack2(acc[0], acc[1]);
    o.y = pack2(acc[2], acc[3]);
    o.z = pack2(acc[4], acc[5]);
    o.w = pack2(acc[6], acc[7]);
    *(uint4*)(smp + (size_t)qh * HD + cq * 8) = o;
  }
}

// ---------------------------------------------------------------------------
extern "C" void kernel_launch(void* const* d_in, const int* in_sizes, int n_in,
                              void* d_out, int out_size, void* d_ws, size_t ws_size,
                              hipStream_t stream) {
  const float* query  = (const float*)d_in[0];
  const float* value  = (const float*)d_in[1];
  const float* qpos   = (const float*)d_in[2];
  const float* refp   = (const float*)d_in[3];
  const float* n1g = (const float*)d_in[6];
  const float* n1b = (const float*)d_in[7];
  const float* Woff = (const float*)d_in[8];
  const float* boff = (const float*)d_in[9];
  const float* Wattn = (const float*)d_in[10];
  const float* battn = (const float*)d_in[11];
  const float* Wval = (const float*)d_in[12];
  const float* bval = (const float*)d_in[13];
  const float* Wout = (const float*)d_in[14];
  const float* bout = (const float*)d_in[15];
  const float* n2g = (const float*)d_in[16];
  const float* n2b = (const float*)d_in[17];
  const float* W1 = (const float*)d_in[18];
  const float* b1 = (const float*)d_in[19];
  const float* W2 = (const float*)d_in[20];
  const float* b2 = (const float*)d_in[21];

  float* out = (float*)d_out;
  char* Wb = (char*)d_ws;

  // workspace layout (time-overlaid; ~152 MB total)
  short* qp_bf   = (short*)Wb;                    // [0,20.48M)  ln1 -> gemm288
  short* iden_bf = (short*)(Wb + 20480000);       // [20.48,40.96M) ln1 -> outproj
  int*   idxB    = (int*)(Wb + 40960000);         // [40.96,61.44M) post -> sample
  unsigned short* wT = (unsigned short*)(Wb + 61440000); // [61.44,102.4M)
  short* res_bf  = (short*)(Wb + 102400000);      // 23.04MB gemm288 -> post
  short* vprjG   = (short*)(Wb + 102400000);      // guard+26.88MB+guard -> sample
  short* vprj_bf = (short*)(Wb + 102400000 + GUARD * D * 2);
  short* h_bf    = (short*)(Wb + 102400000);      // 20.48MB ln2 -> ffn1
  short* smp_bf  = (short*)(Wb + 130000000);      // 20.48MB sample -> outproj
  short* mid_bf  = (short*)Wb;                    // [0,81.92M) ffn1 -> ffn2
  char*  Wbase   = Wb + 150600000;
  short* WT288   = (short*)(Wbase);
  short* WTval   = (short*)(Wbase + 147456);
  short* WTout   = (short*)(Wbase + 278528);
  short* WT1     = (short*)(Wbase + 409600);
  short* WT2     = (short*)(Wbase + 933888);
  float* bias288 = (float*)(Wbase + 1458176);

  // weight prep (single fused kernel)
  k_prep<<<(729376 + 255) / 256, 256, 0, stream>>>(
      Woff, Wattn, Wval, Wout, W1, W2, boff, battn,
      WT288, WTval, WTout, WT1, WT2, bias288);

  // LN1 -> iden(bf16), qp(bf16)
  k_ln1<<<NQ / 4, 256, 0, stream>>>(query, qpos, n1g, n1b, iden_bf, qp_bf);

  // offsets+attn logits GEMM (N=288) -> bf16 res
  k_gemm<4,0,256><<<dim3(3, (NQ + 127) / 128), 256, 0, stream>>>(
      qp_bf, WT288, bias288, nullptr, res_bf, nullptr, nullptr, NQ, 288);
  // softmax + sampling meta
  k_post<<<(NQ * 8 + 255) / 256, 256, 0, stream>>>(
      (const unsigned short*)res_bf, refp, idxB, wT);

  // value proj (fused f32->bf16 A staging) -> bf16 (guard-padded table)
  k_gemm<4,1,256><<<dim3(2, (NV + 127) / 128), 256, 0, stream>>>(
      value, WTval, bval, nullptr, vprj_bf, nullptr, nullptr, NV, 256);

  // deformable sampling -> smp(bf16); 4 qh per wave, 16 per block
  k_sample<<<NQ * NHEAD / 16, 256, 0, stream>>>(vprjG, idxB, wT, smp_bf);

  // out proj + residuals (query f32 + iden bf16) -> x (d_out)
  k_gemm<5,0,256><<<dim3(2, (NQ + 127) / 128), 256, 0, stream>>>(
      smp_bf, WTout, bout, out, nullptr, query, (const float*)iden_bf, NQ, 256);

  // LN2 -> h(bf16)
  k_ln2<<<NQ / 4, 256, 0, stream>>>(out, n2g, n2b, h_bf);

  // FFN1: gelu(h@W1+b1) -> mid(bf16)
  k_gemm<1,0,256><<<dim3(8, (NQ + 127) / 128), 256, 0, stream>>>(
      h_bf, WT1, b1, nullptr, mid_bf, nullptr, nullptr, NQ, 1024);

  // FFN2: x += mid@W2+b2 (in place on d_out)
  k_gemm<3,0,1024><<<dim3(2, (NQ + 127) / 128), 256, 0, stream>>>(
      mid_bf, WT2, b2, out, nullptr, nullptr, nullptr, NQ, 256);
}